// Round 11
// baseline (102.212 us; speedup 1.0000x reference)
//
#include <hip/hip_runtime.h>
#include <hip/hip_bf16.h>

typedef __bf16 bf16_t;
typedef __bf16 bf16x8 __attribute__((ext_vector_type(8)));
typedef __bf16 bf16x4 __attribute__((ext_vector_type(4)));
typedef float f32x4 __attribute__((ext_vector_type(4)));
typedef unsigned int u32;

#define D_MODEL 1024
#define T_SEQ   2048
#define N_HEADS 16

#define WAITVM(N) asm volatile("s_waitcnt vmcnt(" #N ")" ::: "memory")

__device__ __forceinline__ void gload_lds16(const void* g, void* l) {
  __builtin_amdgcn_global_load_lds((const __attribute__((address_space(1))) u32*)g,
                                   (__attribute__((address_space(3))) u32*)l, 16, 0, 0);
}

__device__ __forceinline__ float fast_exp2(float x) {
#if __has_builtin(__builtin_amdgcn_exp2f)
  return __builtin_amdgcn_exp2f(x);
#else
  return __expf(x * 0.69314718056f);
#endif
}

// ---------------- fused fp32->bf16 cast (x + 4 weights) ----------------
struct CastArgs { const float* src[5]; bf16_t* dst[5]; };

__global__ __launch_bounds__(256) void cast_all(CastArgs p) {
  unsigned i = (blockIdx.x * 256u + threadIdx.x) * 4u;
  int seg; unsigned off;
  if (i < 4194304u) { seg = 0; off = i; }
  else { unsigned r = i - 4194304u; seg = 1 + (int)(r >> 20); off = r & 1048575u; }
  const float4 v = *(const float4*)(p.src[seg] + off);
  bf16x4 o = { (bf16_t)v.x, (bf16_t)v.y, (bf16_t)v.z, (bf16_t)v.w };
  *(bf16x4*)(p.dst[seg] + off) = o;
}

#define QSCL 0.18033688011112042f   // 0.125 * log2(e)

// ============== fused QKV: 256x192 tile, BK=64, 4-phase, 512 thr ==============
struct QKVArgs {
  const bf16_t* A;
  const bf16_t* W[3];
  const float* bias[3];
  bf16_t* out[3];
};

__global__ __launch_bounds__(512, 2) void qkv_gemm(QKVArgs p) {
  __shared__ bf16_t lds[2 * 28672];   // [buf][A:16384 | B:12288]

  const int tid = threadIdx.x;
  const int l = tid & 63, wid = tid >> 6;
  const int lh = l >> 4, r15 = l & 15;

  const int lid = blockIdx.x;
  const int bx = lid >> 4, by = lid & 15;
  const int brow = bx * 256;
  const int gcol0 = by * 192;

  const int wr = (wid >> 2) * 128;
  const int wc = (wid & 3) * 48;
  const int wrc = (wr >> 4);
  const int wcc = (wc >> 4);
  const int sA = (lh ^ ((r15 >> 1) & 3)) * 8;
  const int roff = r15 * 32;

  const int srow = l >> 2;
  const int gs = ((l & 3) ^ ((l >> 3) & 3)) * 8;

  f32x4 acc[8][3];
  const f32x4 zero = {0.f, 0.f, 0.f, 0.f};
#pragma unroll
  for (int i = 0; i < 8; ++i)
#pragma unroll
    for (int j = 0; j < 3; ++j) acc[i][j] = zero;

  const bf16_t* A = p.A;

  auto stageA = [&](bf16_t* buf, int k0, int kh) {
#pragma unroll
    for (int i = 0; i < 2; ++i) {
      int c = wid * 2 + i;
      gload_lds16(A + (size_t)(brow + c * 16 + srow) * D_MODEL + k0 + kh * 32 + gs,
                  buf + kh * 8192 + c * 512);
    }
  };
  auto stageB = [&](bf16_t* buf, int k0) {
#pragma unroll
    for (int i = 0; i < 3; ++i) {
      int g = wid * 3 + i;
      int kh = g >= 12;
      int c = g - kh * 12;
      int gcol = gcol0 + c * 16 + srow;
      int z = gcol >> 10;
      const bf16_t* w = (z == 0) ? p.W[0] : ((z == 1) ? p.W[1] : p.W[2]);
      gload_lds16(w + (size_t)(gcol & 1023) * D_MODEL + k0 + kh * 32 + gs,
                  buf + 16384 + kh * 6144 + c * 512);
    }
  };

  stageA(lds, 0, 0);
  stageA(lds, 0, 1);
  stageB(lds, 0);
  WAITVM(0);
  __builtin_amdgcn_s_barrier();

  for (int t = 0; t < 16; ++t) {
    bf16_t* cur = lds + (t & 1) * 28672;
    bf16_t* nxt = lds + ((t + 1) & 1) * 28672;
    const int k1 = (t + 1) * 64;
    const bool more = (t < 15);

    bf16x8 bfr[3][2];
#pragma unroll
    for (int ph = 0; ph < 4; ++ph) {
      bf16x8 a[2][2];
#pragma unroll
      for (int jj = 0; jj < 2; ++jj)
#pragma unroll
        for (int kh = 0; kh < 2; ++kh)
          a[jj][kh] = *(const bf16x8*)(cur + kh * 8192 + (wrc + 2 * ph + jj) * 512 + roff + sA);
      if (ph == 0) {
#pragma unroll
        for (int ni = 0; ni < 3; ++ni)
#pragma unroll
          for (int kh = 0; kh < 2; ++kh)
            bfr[ni][kh] = *(const bf16x8*)(cur + 16384 + kh * 6144 + (wcc + ni) * 512 + roff + sA);
      }
      if (more) {
        if (ph == 0) stageA(nxt, k1, 0);
        else if (ph == 1) stageA(nxt, k1, 1);
        else if (ph == 2) stageB(nxt, k1);
      }
      __builtin_amdgcn_s_barrier();
      __builtin_amdgcn_s_setprio(1);
#pragma unroll
      for (int jj = 0; jj < 2; ++jj)
#pragma unroll
        for (int ni = 0; ni < 3; ++ni) {
          acc[2 * ph + jj][ni] = __builtin_amdgcn_mfma_f32_16x16x32_bf16(a[jj][0], bfr[ni][0], acc[2 * ph + jj][ni], 0, 0, 0);
          acc[2 * ph + jj][ni] = __builtin_amdgcn_mfma_f32_16x16x32_bf16(a[jj][1], bfr[ni][1], acc[2 * ph + jj][ni], 0, 0, 0);
        }
      __builtin_amdgcn_s_setprio(0);
      if (ph == 3 && more) WAITVM(0);
      __builtin_amdgcn_s_barrier();
    }
  }

#pragma unroll
  for (int ni = 0; ni < 3; ++ni) {
    const int col = gcol0 + wc + ni * 16 + r15;
    const int z = col >> 10;
    const int zc = col & 1023;
    const float* bias = (z == 0) ? p.bias[0] : ((z == 1) ? p.bias[1] : p.bias[2]);
    bf16_t* O = (z == 0) ? p.out[0] : ((z == 1) ? p.out[1] : p.out[2]);
    const float bz = bias[zc];
    if (z == 2) {
#pragma unroll
      for (int mi = 0; mi < 8; ++mi) {
        int row0 = brow + wr + mi * 16 + lh * 4;
        int bb = row0 >> 11, t0 = row0 & 2047;
        bf16x4 pk;
#pragma unroll
        for (int j = 0; j < 4; ++j) pk[j] = (bf16_t)(acc[mi][ni][j] + bz);
        *(bf16x4*)(O + (size_t)bb * (D_MODEL * T_SEQ) + (size_t)zc * T_SEQ + t0) = pk;
      }
    } else if (z == 0) {
#pragma unroll
      for (int mi = 0; mi < 8; ++mi) {
        int row0 = brow + wr + mi * 16 + lh * 4;
#pragma unroll
        for (int j = 0; j < 4; ++j)
          O[(size_t)(row0 + j) * D_MODEL + zc] = (bf16_t)((acc[mi][ni][j] + bz) * QSCL);
      }
    } else {
#pragma unroll
      for (int mi = 0; mi < 8; ++mi) {
        int row0 = brow + wr + mi * 16 + lh * 4;
#pragma unroll
        for (int j = 0; j < 4; ++j)
          O[(size_t)(row0 + j) * D_MODEL + zc] = (bf16_t)(acc[mi][ni][j] + bz);
      }
    }
  }
}

// ---------------- 64x128 GEMM (out projection) ----------------
__device__ __forceinline__ void stage_ab64(
    const bf16_t* __restrict__ A, const bf16_t* __restrict__ W,
    bf16_t* buf, int brow, int bcol, int k0, int w, int l) {
  const int srow = l >> 2;
  const int scol = ((l & 3) ^ ((l >> 3) & 3)) * 8;
#pragma unroll
  for (int i = 0; i < 3; ++i) {
    int ch = w * 3 + i;
    const bf16_t* src = (ch < 4)
      ? A + (size_t)(brow + ch * 16 + srow) * D_MODEL + k0 + scol
      : W + (size_t)(bcol + (ch - 4) * 16 + srow) * D_MODEL + k0 + scol;
    gload_lds16(src, buf + ch * 512);
  }
}

__device__ __forceinline__ void gemm_tile_64(
    const bf16_t* __restrict__ A, const bf16_t* __restrict__ W,
    bf16_t* bufs, int brow, int bcol, f32x4 acc[2][4])
{
  const int tid = threadIdx.x;
  const int l = tid & 63, w = tid >> 6;
  const int wr = (w >> 1) * 32, wc = (w & 1) * 64;
  const int lh = l >> 4, r15 = l & 15;
  const int NS = D_MODEL / 32;

  stage_ab64(A, W, bufs + 0 * 6144, brow, bcol, 0, w, l);
  stage_ab64(A, W, bufs + 1 * 6144, brow, bcol, 32, w, l);

  for (int t = 0; t < NS; ++t) {
    bf16_t* bb = bufs + (t % 3) * 6144;
    if (t + 2 < NS) {
      stage_ab64(A, W, bufs + ((t + 2) % 3) * 6144, brow, bcol, (t + 2) * 32, w, l);
      WAITVM(6);
    } else if (t + 1 < NS) {
      WAITVM(3);
    } else {
      WAITVM(0);
    }
    __builtin_amdgcn_s_barrier();

    bf16x8 af[2], bfr[4];
#pragma unroll
    for (int mi = 0; mi < 2; ++mi) {
      int rr = wr + mi * 16 + r15;
      int s = lh ^ ((rr >> 1) & 3);
      af[mi] = *(const bf16x8*)(bb + rr * 32 + s * 8);
    }
#pragma unroll
    for (int ni = 0; ni < 4; ++ni) {
      int rr = wc + ni * 16 + r15;
      int s = lh ^ ((rr >> 1) & 3);
      bfr[ni] = *(const bf16x8*)(bb + 2048 + rr * 32 + s * 8);
    }
    __builtin_amdgcn_s_setprio(1);
#pragma unroll
    for (int mi = 0; mi < 2; ++mi)
#pragma unroll
      for (int ni = 0; ni < 4; ++ni)
        acc[mi][ni] = __builtin_amdgcn_mfma_f32_16x16x32_bf16(af[mi], bfr[ni], acc[mi][ni], 0, 0, 0);
    __builtin_amdgcn_s_setprio(0);
    __builtin_amdgcn_s_barrier();
  }
}

__global__ __launch_bounds__(256) void out_gemm(
    const bf16_t* __restrict__ A, const bf16_t* __restrict__ W,
    const float* __restrict__ bias, float* __restrict__ O)
{
  __shared__ bf16_t bufs[3 * 6144];
  f32x4 acc[2][4];
  f32x4 zero = {0.f, 0.f, 0.f, 0.f};
#pragma unroll
  for (int i = 0; i < 2; ++i)
#pragma unroll
    for (int j = 0; j < 4; ++j) acc[i][j] = zero;

  const int brow = blockIdx.x * 64, bcol = blockIdx.y * 128;
  gemm_tile_64(A, W, bufs, brow, bcol, acc);

  const int tid = threadIdx.x, l = tid & 63, w = tid >> 6;
  const int wr = (w >> 1) * 32, wc = (w & 1) * 64, lh = l >> 4, r15 = l & 15;
#pragma unroll
  for (int ni = 0; ni < 4; ++ni) {
    int col = bcol + wc + ni * 16 + r15;
    float bz = bias[col];
#pragma unroll
    for (int mi = 0; mi < 2; ++mi) {
      int row0 = brow + wr + mi * 16 + lh * 4;
#pragma unroll
      for (int j = 0; j < 4; ++j)
        O[(size_t)(row0 + j) * D_MODEL + col] = acc[mi][ni][j] + bz;
    }
  }
}

// ---------------- causal flash attention: unfolded + kv-split ----------------
// qt<=15: one block, direct Om write. qt>=16: two blocks splitting the kv range
// (m=0 softmax is linear, so partials are additive); each writes unnormalized
// f32 O (64x64) + row-l to a dedicated ws slot; combine kernel finishes.
// 48-entry LPT schedule (chains sorted desc, all <= 8 tiles of 128 kv).
// mode: 0 = single, 1 = split lower half, 2 = split upper half (owns diagonal).
__device__ const unsigned char SCHED[48] = {
  62, 94, 63, 95, 92, 93, 15, 14,
  60, 61, 58, 90, 59, 91, 88, 89, 13, 12,
  56, 57, 54, 86, 55, 87, 84, 85, 11, 10,
  52, 53, 50, 82, 51, 83, 80, 81, 9, 8,
  48, 49, 7, 6,
  5, 4,
  3, 2,
  1, 0
};

__device__ __forceinline__ void stage_k128(const bf16_t* Kg, bf16_t* Kd, int kv0, int w, int l) {
#pragma unroll
  for (int i = 0; i < 4; ++i) {
    int c = w * 4 + i;
    int row = c * 8 + (l >> 3);
    int gcol = ((l & 7) ^ ((l >> 3) & 7)) * 8;
    gload_lds16(Kg + (size_t)(kv0 + row) * D_MODEL + gcol, Kd + c * 512);
  }
}
__device__ __forceinline__ void stage_v128(const bf16_t* Vg, bf16_t* Vd, int kv0, int w, int l) {
#pragma unroll
  for (int i = 0; i < 4; ++i) {
    int c = w * 4 + i;
    int drow = c * 4 + (l >> 4);
    int gkv = ((l & 15) ^ (drow & 15)) * 8;
    gload_lds16(Vg + (size_t)drow * T_SEQ + kv0 + gkv, Vd + c * 512);
  }
}

__global__ __launch_bounds__(256) void flash_attn(
    const bf16_t* __restrict__ Qm, const bf16_t* __restrict__ Km,
    const bf16_t* __restrict__ Vtg, bf16_t* __restrict__ Om,
    float* __restrict__ Pw)
{
  __shared__ bf16_t Kls[128 * 64];
  __shared__ bf16_t Vls[64 * 128];
  __shared__ bf16_t Pls[4][2][16 * 72];

  const int tid = threadIdx.x, l = tid & 63, w = tid >> 6;
  const int lh = l >> 4, r15 = l & 15;

  const int lid = blockIdx.x;
  const int e = SCHED[lid >> 5];
  const int qt = e & 31;
  const int mode = e >> 5;
  const int bh = lid & 31;              // bh%8 == lid%8 -> head pinned to one XCD
  const int b = bh >> 4, h = bh & 15;
  const int nT = (qt >> 1) + 1;
  const int h0 = nT >> 1;
  const int t0 = (mode == 2) ? h0 : 0;
  const int t1 = (mode == 1) ? h0 : nT;
  const bool split = (mode != 0);
  const int s = (mode == 2) ? 1 : 0;

  const size_t baseQ = (size_t)b * T_SEQ * D_MODEL + h * 64;
  const size_t baseVt = (size_t)b * (D_MODEL * T_SEQ) + (size_t)(h * 64) * T_SEQ;
  const bf16_t* Kg = Km + baseQ;
  const bf16_t* Vg = Vtg + baseVt;

  const int qw = qt * 64 + w * 16;
  const int qrow = qw + r15;

  bf16x8 qf[2];
  {
    const bf16_t* qp = Qm + baseQ + (size_t)(qw + r15) * D_MODEL + lh * 8;
    qf[0] = *(const bf16x8*)(qp);
    qf[1] = *(const bf16x8*)(qp + 32);
  }

  float l_r = 0.f;
  f32x4 o_acc[4];
  const f32x4 zero = {0.f, 0.f, 0.f, 0.f};
#pragma unroll
  for (int n = 0; n < 4; ++n) o_acc[n] = zero;

  bf16_t* PA = &Pls[w][0][0];
  bf16_t* PB = &Pls[w][1][0];

  stage_k128(Kg, Kls, t0 * 128, w, l);
  stage_v128(Vg, Vls, t0 * 128, w, l);
  WAITVM(0);
  __builtin_amdgcn_s_barrier();

  for (int t = t0; t < t1; ++t) {
    const int kv0 = t * 128;
    const bool more = (t + 1 < t1);
    const bool diag = (t == nT - 1);          // only mode 0/2 ever reach it
    const bool skip2 = diag && ((qt & 1) == 0);

    // ---- S^T = K Q^T ----
    f32x4 sf[8];
    auto qk_n = [&](int n) {
      const int kvc = n * 16 + r15;
      const int sw = kvc & 7;
      bf16x8 kf0 = *(const bf16x8*)(Kls + kvc * 64 + ((lh ^ sw) * 8));
      bf16x8 kf1 = *(const bf16x8*)(Kls + kvc * 64 + (((4 + lh) ^ sw) * 8));
      f32x4 a = zero;
      a = __builtin_amdgcn_mfma_f32_16x16x32_bf16(kf0, qf[0], a, 0, 0, 0);
      a = __builtin_amdgcn_mfma_f32_16x16x32_bf16(kf1, qf[1], a, 0, 0, 0);
      sf[n] = a;
    };
    __builtin_amdgcn_s_setprio(1);
#pragma unroll
    for (int n = 0; n < 4; ++n) qk_n(n);
    __builtin_amdgcn_s_setprio(0);
    if (!skip2) {
      __builtin_amdgcn_s_setprio(1);
#pragma unroll
      for (int n = 4; n < 8; ++n) qk_n(n);
      __builtin_amdgcn_s_setprio(0);
    }

    __builtin_amdgcn_s_barrier();          // all waves done reading K
    if (more) stage_k128(Kg, Kls, kv0 + 128, w, l);

    // ---- softmax halves -> P dbuf (per-wave, no barrier needed) ----
    auto sm_half = [&](int hh, bf16_t* P, bool dm) {
#pragma unroll
      for (int n2 = 0; n2 < 4; ++n2) {
        const int n = hh * 4 + n2;
        float pv[4];
#pragma unroll
        for (int j = 0; j < 4; ++j) {
          float pp = fast_exp2(sf[n][j]);
          if (dm) {
            const int kvcol = kv0 + hh * 64 + n2 * 16 + lh * 4 + j;
            if (kvcol > qrow) pp = 0.f;
          }
          pv[j] = pp;
          l_r += pp;
        }
        bf16x4 pk = { (bf16_t)pv[0], (bf16_t)pv[1], (bf16_t)pv[2], (bf16_t)pv[3] };
        *(bf16x4*)(P + r15 * 72 + (n2 * 2 + (lh >> 1)) * 8 + (lh & 1) * 4) = pk;
      }
    };
    sm_half(0, PA, diag);
    if (!skip2) sm_half(1, PB, diag);

    if (more) WAITVM(4); else WAITVM(0);   // V(t) landed (oldest); K(t+1) may fly

    // ---- O += P V ----
    auto pv_half = [&](int hh, const bf16_t* P) {
      bf16x8 pa0 = *(const bf16x8*)(P + r15 * 72 + lh * 8);
      bf16x8 pa1 = *(const bf16x8*)(P + r15 * 72 + (4 + lh) * 8);
      __builtin_amdgcn_s_setprio(1);
#pragma unroll
      for (int nD = 0; nD < 4; ++nD) {
        const int d = nD * 16 + r15;
        const int b0 = (hh * 8 + lh) ^ r15;
        const int b1 = (hh * 8 + 4 + lh) ^ r15;
        bf16x8 vf0 = *(const bf16x8*)(Vls + d * 128 + b0 * 8);
        bf16x8 vf1 = *(const bf16x8*)(Vls + d * 128 + b1 * 8);
        o_acc[nD] = __builtin_amdgcn_mfma_f32_16x16x32_bf16(vf0, pa0, o_acc[nD], 0, 0, 0);
        o_acc[nD] = __builtin_amdgcn_mfma_f32_16x16x32_bf16(vf1, pa1, o_acc[nD], 0, 0, 0);
      }
      __builtin_amdgcn_s_setprio(0);
    };
    pv_half(0, PA);
    if (!skip2) pv_half(1, PB);

    __builtin_amdgcn_s_barrier();          // all waves done reading V(t)
    if (more) {
      stage_v128(Vg, Vls, kv0 + 128, w, l);
      WAITVM(4);                           // K(t+1) landed; V(t+1) stays in flight
    }
  }

  // ---- epilogue ----
  float ls = l_r;
  ls += __shfl_xor(ls, 16, 64);
  ls += __shfl_xor(ls, 32, 64);

  if (!split) {
    const float invl = 1.f / ls;
    bf16_t* orow = Om + (size_t)(b * T_SEQ + qw + r15) * D_MODEL + h * 64;
#pragma unroll
    for (int n = 0; n < 4; ++n) {
      bf16x4 pk = { (bf16_t)(o_acc[n][0] * invl), (bf16_t)(o_acc[n][1] * invl),
                    (bf16_t)(o_acc[n][2] * invl), (bf16_t)(o_acc[n][3] * invl) };
      *(bf16x4*)(orow + n * 16 + lh * 4) = pk;
    }
  } else {
    float* slot = Pw + ((size_t)((qt - 16) * 32 + bh) * 2 + s) * 4160;
    float* prow = slot + (w * 16 + r15) * 64;
#pragma unroll
    for (int n = 0; n < 4; ++n)
      *(f32x4*)(prow + n * 16 + lh * 4) = o_acc[n];
    if (lh == 0) slot[4096 + w * 16 + r15] = ls;
  }
}

// ---------------- combine partial attention outputs (split qt) ----------------
__global__ __launch_bounds__(256) void combine_attn(
    const float* __restrict__ Pw, bf16_t* __restrict__ Om)
{
  const int g = blockIdx.x;              // 0..511
  const int qt = 16 + (g >> 5);
  const int bh = g & 31;
  const int b = bh >> 4, h = bh & 15;
  const int row = threadIdx.x >> 2;
  const int cs = (threadIdx.x & 3) * 16;

  const float* s0 = Pw + (size_t)((qt - 16) * 32 + bh) * 2 * 4160;
  const float* s1 = s0 + 4160;
  const float invl = 1.f / (s0[4096 + row] + s1[4096 + row]);

  bf16_t* orow = Om + (size_t)(b * T_SEQ + qt * 64 + row) * D_MODEL + h * 64 + cs;
#pragma unroll
  for (int k4 = 0; k4 < 4; ++k4) {
    float4 a = *(const float4*)(s0 + row * 64 + cs + k4 * 4);
    float4 c = *(const float4*)(s1 + row * 64 + cs + k4 * 4);
    bf16x4 pk = { (bf16_t)((a.x + c.x) * invl), (bf16_t)((a.y + c.y) * invl),
                  (bf16_t)((a.z + c.z) * invl), (bf16_t)((a.w + c.w) * invl) };
    *(bf16x4*)(orow + k4 * 4) = pk;
  }
}

// ---------------- host launch ----------------
extern "C" void kernel_launch(void* const* d_in, const int* in_sizes, int n_in,
                              void* d_out, int out_size, void* d_ws, size_t ws_size,
                              hipStream_t stream) {
  const float* x  = (const float*)d_in[0];
  const float* wq = (const float*)d_in[1];
  const float* bq = (const float*)d_in[2];
  const float* wk = (const float*)d_in[3];
  const float* bk = (const float*)d_in[4];
  const float* wv = (const float*)d_in[5];
  const float* bv = (const float*)d_in[6];
  const float* wo = (const float*)d_in[7];
  const float* bo = (const float*)d_in[8];

  char* ws = (char*)d_ws;
  const size_t MB = 1024 * 1024;
  bf16_t* xb  = (bf16_t*)(ws);
  bf16_t* wqb = (bf16_t*)(ws + 8 * MB);
  bf16_t* wkb = (bf16_t*)(ws + 10 * MB);
  bf16_t* wvb = (bf16_t*)(ws + 12 * MB);
  bf16_t* wob = (bf16_t*)(ws + 14 * MB);
  bf16_t* qb  = (bf16_t*)(ws + 16 * MB);
  bf16_t* kb  = (bf16_t*)(ws + 24 * MB);
  bf16_t* vtb = (bf16_t*)(ws + 32 * MB);  // V^T [B][1024][2048]
  bf16_t* ob  = (bf16_t*)(ws + 40 * MB);
  float* pbuf = (float*)(ws + 64 * MB);   // 1024 slots x 4160 f32 = ~17 MB

  CastArgs ca;
  ca.src[0] = x;  ca.dst[0] = xb;
  ca.src[1] = wq; ca.dst[1] = wqb;
  ca.src[2] = wk; ca.dst[2] = wkb;
  ca.src[3] = wv; ca.dst[3] = wvb;
  ca.src[4] = wo; ca.dst[4] = wob;
  cast_all<<<8192, 256, 0, stream>>>(ca);

  QKVArgs qa;
  qa.A = xb;
  qa.W[0] = wqb; qa.W[1] = wkb; qa.W[2] = wvb;
  qa.bias[0] = bq; qa.bias[1] = bk; qa.bias[2] = bv;
  qa.out[0] = qb; qa.out[1] = kb; qa.out[2] = vtb;
  qkv_gemm<<<256, 512, 0, stream>>>(qa);

  flash_attn<<<1536, 256, 0, stream>>>(qb, kb, vtb, ob, pbuf);
  combine_attn<<<512, 256, 0, stream>>>(pbuf, ob);

  out_gemm<<<dim3(64, 8), 256, 0, stream>>>(ob, wob, bo, (float*)d_out);
}

// Round 12
// 101.075 us; speedup vs baseline: 1.0112x; 1.0112x over previous
//
#include <hip/hip_runtime.h>
#include <hip/hip_bf16.h>

typedef __bf16 bf16_t;
typedef __bf16 bf16x8 __attribute__((ext_vector_type(8)));
typedef __bf16 bf16x4 __attribute__((ext_vector_type(4)));
typedef float f32x4 __attribute__((ext_vector_type(4)));
typedef unsigned int u32;

#define D_MODEL 1024
#define T_SEQ   2048
#define N_HEADS 16

#define WAITVM(N) asm volatile("s_waitcnt vmcnt(" #N ")" ::: "memory")

__device__ __forceinline__ void gload_lds16(const void* g, void* l) {
  __builtin_amdgcn_global_load_lds((const __attribute__((address_space(1))) u32*)g,
                                   (__attribute__((address_space(3))) u32*)l, 16, 0, 0);
}

__device__ __forceinline__ float fast_exp2(float x) {
#if __has_builtin(__builtin_amdgcn_exp2f)
  return __builtin_amdgcn_exp2f(x);
#else
  return __expf(x * 0.69314718056f);
#endif
}

// ---------------- fused fp32->bf16 cast (x + 4 weights) ----------------
struct CastArgs { const float* src[5]; bf16_t* dst[5]; };

__global__ __launch_bounds__(256) void cast_all(CastArgs p) {
  unsigned i = (blockIdx.x * 256u + threadIdx.x) * 4u;
  int seg; unsigned off;
  if (i < 4194304u) { seg = 0; off = i; }
  else { unsigned r = i - 4194304u; seg = 1 + (int)(r >> 20); off = r & 1048575u; }
  const float4 v = *(const float4*)(p.src[seg] + off);
  bf16x4 o = { (bf16_t)v.x, (bf16_t)v.y, (bf16_t)v.z, (bf16_t)v.w };
  *(bf16x4*)(p.dst[seg] + off) = o;
}

#define QSCL 0.18033688011112042f   // 0.125 * log2(e)

// ============== fused QKV: 256x192 tile, BK=64, 4-phase, 512 thr ==============
struct QKVArgs {
  const bf16_t* A;
  const bf16_t* W[3];
  const float* bias[3];
  bf16_t* out[3];
};

__global__ __launch_bounds__(512, 2) void qkv_gemm(QKVArgs p) {
  __shared__ bf16_t lds[2 * 28672];   // [buf][A:16384 | B:12288]

  const int tid = threadIdx.x;
  const int l = tid & 63, wid = tid >> 6;
  const int lh = l >> 4, r15 = l & 15;

  const int lid = blockIdx.x;
  const int bx = lid >> 4, by = lid & 15;
  const int brow = bx * 256;
  const int gcol0 = by * 192;

  const int wr = (wid >> 2) * 128;
  const int wc = (wid & 3) * 48;
  const int wrc = (wr >> 4);
  const int wcc = (wc >> 4);
  const int sA = (lh ^ ((r15 >> 1) & 3)) * 8;
  const int roff = r15 * 32;

  const int srow = l >> 2;
  const int gs = ((l & 3) ^ ((l >> 3) & 3)) * 8;

  f32x4 acc[8][3];
  const f32x4 zero = {0.f, 0.f, 0.f, 0.f};
#pragma unroll
  for (int i = 0; i < 8; ++i)
#pragma unroll
    for (int j = 0; j < 3; ++j) acc[i][j] = zero;

  const bf16_t* A = p.A;

  auto stageA = [&](bf16_t* buf, int k0, int kh) {
#pragma unroll
    for (int i = 0; i < 2; ++i) {
      int c = wid * 2 + i;
      gload_lds16(A + (size_t)(brow + c * 16 + srow) * D_MODEL + k0 + kh * 32 + gs,
                  buf + kh * 8192 + c * 512);
    }
  };
  auto stageB = [&](bf16_t* buf, int k0) {
#pragma unroll
    for (int i = 0; i < 3; ++i) {
      int g = wid * 3 + i;
      int kh = g >= 12;
      int c = g - kh * 12;
      int gcol = gcol0 + c * 16 + srow;
      int z = gcol >> 10;
      const bf16_t* w = (z == 0) ? p.W[0] : ((z == 1) ? p.W[1] : p.W[2]);
      gload_lds16(w + (size_t)(gcol & 1023) * D_MODEL + k0 + kh * 32 + gs,
                  buf + 16384 + kh * 6144 + c * 512);
    }
  };

  stageA(lds, 0, 0);
  stageA(lds, 0, 1);
  stageB(lds, 0);
  WAITVM(0);
  __builtin_amdgcn_s_barrier();

  for (int t = 0; t < 16; ++t) {
    bf16_t* cur = lds + (t & 1) * 28672;
    bf16_t* nxt = lds + ((t + 1) & 1) * 28672;
    const int k1 = (t + 1) * 64;
    const bool more = (t < 15);

    bf16x8 bfr[3][2];
#pragma unroll
    for (int ph = 0; ph < 4; ++ph) {
      bf16x8 a[2][2];
#pragma unroll
      for (int jj = 0; jj < 2; ++jj)
#pragma unroll
        for (int kh = 0; kh < 2; ++kh)
          a[jj][kh] = *(const bf16x8*)(cur + kh * 8192 + (wrc + 2 * ph + jj) * 512 + roff + sA);
      if (ph == 0) {
#pragma unroll
        for (int ni = 0; ni < 3; ++ni)
#pragma unroll
          for (int kh = 0; kh < 2; ++kh)
            bfr[ni][kh] = *(const bf16x8*)(cur + 16384 + kh * 6144 + (wcc + ni) * 512 + roff + sA);
      }
      if (more) {
        if (ph == 0) stageA(nxt, k1, 0);
        else if (ph == 1) stageA(nxt, k1, 1);
        else if (ph == 2) stageB(nxt, k1);
      }
      __builtin_amdgcn_s_barrier();
      __builtin_amdgcn_s_setprio(1);
#pragma unroll
      for (int jj = 0; jj < 2; ++jj)
#pragma unroll
        for (int ni = 0; ni < 3; ++ni) {
          acc[2 * ph + jj][ni] = __builtin_amdgcn_mfma_f32_16x16x32_bf16(a[jj][0], bfr[ni][0], acc[2 * ph + jj][ni], 0, 0, 0);
          acc[2 * ph + jj][ni] = __builtin_amdgcn_mfma_f32_16x16x32_bf16(a[jj][1], bfr[ni][1], acc[2 * ph + jj][ni], 0, 0, 0);
        }
      __builtin_amdgcn_s_setprio(0);
      if (ph == 3 && more) WAITVM(0);
      __builtin_amdgcn_s_barrier();
    }
  }

#pragma unroll
  for (int ni = 0; ni < 3; ++ni) {
    const int col = gcol0 + wc + ni * 16 + r15;
    const int z = col >> 10;
    const int zc = col & 1023;
    const float* bias = (z == 0) ? p.bias[0] : ((z == 1) ? p.bias[1] : p.bias[2]);
    bf16_t* O = (z == 0) ? p.out[0] : ((z == 1) ? p.out[1] : p.out[2]);
    const float bz = bias[zc];
    if (z == 2) {
#pragma unroll
      for (int mi = 0; mi < 8; ++mi) {
        int row0 = brow + wr + mi * 16 + lh * 4;
        int bb = row0 >> 11, t0 = row0 & 2047;
        bf16x4 pk;
#pragma unroll
        for (int j = 0; j < 4; ++j) pk[j] = (bf16_t)(acc[mi][ni][j] + bz);
        *(bf16x4*)(O + (size_t)bb * (D_MODEL * T_SEQ) + (size_t)zc * T_SEQ + t0) = pk;
      }
    } else if (z == 0) {
#pragma unroll
      for (int mi = 0; mi < 8; ++mi) {
        int row0 = brow + wr + mi * 16 + lh * 4;
#pragma unroll
        for (int j = 0; j < 4; ++j)
          O[(size_t)(row0 + j) * D_MODEL + zc] = (bf16_t)((acc[mi][ni][j] + bz) * QSCL);
      }
    } else {
#pragma unroll
      for (int mi = 0; mi < 8; ++mi) {
        int row0 = brow + wr + mi * 16 + lh * 4;
#pragma unroll
        for (int j = 0; j < 4; ++j)
          O[(size_t)(row0 + j) * D_MODEL + zc] = (bf16_t)(acc[mi][ni][j] + bz);
      }
    }
  }
}

// ---------------- 64x128 GEMM (out projection) ----------------
__device__ __forceinline__ void stage_ab64(
    const bf16_t* __restrict__ A, const bf16_t* __restrict__ W,
    bf16_t* buf, int brow, int bcol, int k0, int w, int l) {
  const int srow = l >> 2;
  const int scol = ((l & 3) ^ ((l >> 3) & 3)) * 8;
#pragma unroll
  for (int i = 0; i < 3; ++i) {
    int ch = w * 3 + i;
    const bf16_t* src = (ch < 4)
      ? A + (size_t)(brow + ch * 16 + srow) * D_MODEL + k0 + scol
      : W + (size_t)(bcol + (ch - 4) * 16 + srow) * D_MODEL + k0 + scol;
    gload_lds16(src, buf + ch * 512);
  }
}

__device__ __forceinline__ void gemm_tile_64(
    const bf16_t* __restrict__ A, const bf16_t* __restrict__ W,
    bf16_t* bufs, int brow, int bcol, f32x4 acc[2][4])
{
  const int tid = threadIdx.x;
  const int l = tid & 63, w = tid >> 6;
  const int wr = (w >> 1) * 32, wc = (w & 1) * 64;
  const int lh = l >> 4, r15 = l & 15;
  const int NS = D_MODEL / 32;

  stage_ab64(A, W, bufs + 0 * 6144, brow, bcol, 0, w, l);
  stage_ab64(A, W, bufs + 1 * 6144, brow, bcol, 32, w, l);

  for (int t = 0; t < NS; ++t) {
    bf16_t* bb = bufs + (t % 3) * 6144;
    if (t + 2 < NS) {
      stage_ab64(A, W, bufs + ((t + 2) % 3) * 6144, brow, bcol, (t + 2) * 32, w, l);
      WAITVM(6);
    } else if (t + 1 < NS) {
      WAITVM(3);
    } else {
      WAITVM(0);
    }
    __builtin_amdgcn_s_barrier();

    bf16x8 af[2], bfr[4];
#pragma unroll
    for (int mi = 0; mi < 2; ++mi) {
      int rr = wr + mi * 16 + r15;
      int s = lh ^ ((rr >> 1) & 3);
      af[mi] = *(const bf16x8*)(bb + rr * 32 + s * 8);
    }
#pragma unroll
    for (int ni = 0; ni < 4; ++ni) {
      int rr = wc + ni * 16 + r15;
      int s = lh ^ ((rr >> 1) & 3);
      bfr[ni] = *(const bf16x8*)(bb + 2048 + rr * 32 + s * 8);
    }
    __builtin_amdgcn_s_setprio(1);
#pragma unroll
    for (int mi = 0; mi < 2; ++mi)
#pragma unroll
      for (int ni = 0; ni < 4; ++ni)
        acc[mi][ni] = __builtin_amdgcn_mfma_f32_16x16x32_bf16(af[mi], bfr[ni], acc[mi][ni], 0, 0, 0);
    __builtin_amdgcn_s_setprio(0);
    __builtin_amdgcn_s_barrier();
  }
}

__global__ __launch_bounds__(256) void out_gemm(
    const bf16_t* __restrict__ A, const bf16_t* __restrict__ W,
    const float* __restrict__ bias, float* __restrict__ O)
{
  __shared__ bf16_t bufs[3 * 6144];
  f32x4 acc[2][4];
  f32x4 zero = {0.f, 0.f, 0.f, 0.f};
#pragma unroll
  for (int i = 0; i < 2; ++i)
#pragma unroll
    for (int j = 0; j < 4; ++j) acc[i][j] = zero;

  const int brow = blockIdx.x * 64, bcol = blockIdx.y * 128;
  gemm_tile_64(A, W, bufs, brow, bcol, acc);

  const int tid = threadIdx.x, l = tid & 63, w = tid >> 6;
  const int wr = (w >> 1) * 32, wc = (w & 1) * 64, lh = l >> 4, r15 = l & 15;
#pragma unroll
  for (int ni = 0; ni < 4; ++ni) {
    int col = bcol + wc + ni * 16 + r15;
    float bz = bias[col];
#pragma unroll
    for (int mi = 0; mi < 2; ++mi) {
      int row0 = brow + wr + mi * 16 + lh * 4;
#pragma unroll
      for (int j = 0; j < 4; ++j)
        O[(size_t)(row0 + j) * D_MODEL + col] = acc[mi][ni][j] + bz;
    }
  }
}

// ---------------- causal flash attention: braided 128q x 128kv ----------------
// 512 blocks: g = lid>>5, qt = (g<8)?15-g:g-8 (CU pairing sums to 17 units),
// bh = lid&31 (head pinned to one XCD). Block = 128 q rows; wave w owns two
// 16-row sub-tiles: A at qt*128+w*16, B at qt*128+64+w*16. Per 128-kv tile the
// two chains braid: QK(A),sm(A),QK(B) | pv(A),sm(B),pv(B) so MFMA latency hides
// exp chains. K/V single-buffered with sound vmcnt(0)+barrier handshakes.
__device__ __forceinline__ void stage_k128(const bf16_t* Kg, bf16_t* Kd, int kv0, int w, int l) {
#pragma unroll
  for (int i = 0; i < 4; ++i) {
    int c = w * 4 + i;
    int row = c * 8 + (l >> 3);
    int gcol = ((l & 7) ^ ((l >> 3) & 7)) * 8;
    gload_lds16(Kg + (size_t)(kv0 + row) * D_MODEL + gcol, Kd + c * 512);
  }
}
__device__ __forceinline__ void stage_v128(const bf16_t* Vg, bf16_t* Vd, int kv0, int w, int l) {
#pragma unroll
  for (int i = 0; i < 4; ++i) {
    int c = w * 4 + i;
    int drow = c * 4 + (l >> 4);
    int gkv = ((l & 15) ^ (drow & 15)) * 8;
    gload_lds16(Vg + (size_t)drow * T_SEQ + kv0 + gkv, Vd + c * 512);
  }
}

__global__ __launch_bounds__(256) void flash_attn(
    const bf16_t* __restrict__ Qm, const bf16_t* __restrict__ Km,
    const bf16_t* __restrict__ Vtg, bf16_t* __restrict__ Om)
{
  __shared__ bf16_t Kls[128 * 64];
  __shared__ bf16_t Vls[64 * 128];
  __shared__ bf16_t Pls[4][2][16 * 72];

  const int tid = threadIdx.x, l = tid & 63, w = tid >> 6;
  const int lh = l >> 4, r15 = l & 15;

  const int lid = blockIdx.x;
  const int g = lid >> 5;
  const int qt = (g < 8) ? (15 - g) : (g - 8);   // balanced LPT pairing
  const int bh = lid & 31;                        // head pinned to one XCD
  const int b = bh >> 4, h = bh & 15;
  const int nT = qt + 1;

  const size_t baseQ = (size_t)b * T_SEQ * D_MODEL + h * 64;
  const size_t baseVt = (size_t)b * (D_MODEL * T_SEQ) + (size_t)(h * 64) * T_SEQ;
  const bf16_t* Kg = Km + baseQ;
  const bf16_t* Vg = Vtg + baseVt;

  const int qA = qt * 128 + w * 16;
  const int qB = qA + 64;
  const int qrowA = qA + r15;
  const int qrowB = qB + r15;

  bf16x8 qfA[2], qfB[2];
  {
    const bf16_t* qp = Qm + baseQ + (size_t)qrowA * D_MODEL + lh * 8;
    qfA[0] = *(const bf16x8*)(qp);
    qfA[1] = *(const bf16x8*)(qp + 32);
    const bf16_t* qp2 = Qm + baseQ + (size_t)qrowB * D_MODEL + lh * 8;
    qfB[0] = *(const bf16x8*)(qp2);
    qfB[1] = *(const bf16x8*)(qp2 + 32);
  }

  float l_A = 0.f, l_B = 0.f;
  f32x4 oA[4], oB[4];
  const f32x4 zero = {0.f, 0.f, 0.f, 0.f};
#pragma unroll
  for (int n = 0; n < 4; ++n) { oA[n] = zero; oB[n] = zero; }

  bf16_t* PA = &Pls[w][0][0];
  bf16_t* PB = &Pls[w][1][0];

  stage_k128(Kg, Kls, 0, w, l);
  stage_v128(Vg, Vls, 0, w, l);
  WAITVM(0);
  __builtin_amdgcn_s_barrier();

  for (int t = 0; t < nT; ++t) {
    const int kv0 = t * 128;
    const bool more = (t + 1 < nT);
    const bool last = (t == nT - 1);

    auto qk_n = [&](const bf16x8* qf, int n, f32x4* sf) {
      const int kvc = n * 16 + r15;
      const int sw = kvc & 7;
      bf16x8 kf0 = *(const bf16x8*)(Kls + kvc * 64 + ((lh ^ sw) * 8));
      bf16x8 kf1 = *(const bf16x8*)(Kls + kvc * 64 + (((4 + lh) ^ sw) * 8));
      f32x4 a = zero;
      a = __builtin_amdgcn_mfma_f32_16x16x32_bf16(kf0, qf[0], a, 0, 0, 0);
      a = __builtin_amdgcn_mfma_f32_16x16x32_bf16(kf1, qf[1], a, 0, 0, 0);
      sf[n] = a;
    };
    auto sm_half = [&](const f32x4* sf, int hh, bf16_t* P, int qrow, bool dm, float& lr) {
#pragma unroll
      for (int n2 = 0; n2 < 4; ++n2) {
        const int n = hh * 4 + n2;
        float pv[4];
#pragma unroll
        for (int j = 0; j < 4; ++j) {
          float pp = fast_exp2(sf[n][j]);
          if (dm) {
            const int kvcol = kv0 + hh * 64 + n2 * 16 + lh * 4 + j;
            if (kvcol > qrow) pp = 0.f;
          }
          pv[j] = pp;
          lr += pp;
        }
        bf16x4 pk = { (bf16_t)pv[0], (bf16_t)pv[1], (bf16_t)pv[2], (bf16_t)pv[3] };
        *(bf16x4*)(P + r15 * 72 + (n2 * 2 + (lh >> 1)) * 8 + (lh & 1) * 4) = pk;
      }
    };
    auto pv_half = [&](int hh, const bf16_t* P, f32x4* o_acc) {
      bf16x8 pa0 = *(const bf16x8*)(P + r15 * 72 + lh * 8);
      bf16x8 pa1 = *(const bf16x8*)(P + r15 * 72 + (4 + lh) * 8);
      __builtin_amdgcn_s_setprio(1);
#pragma unroll
      for (int nD = 0; nD < 4; ++nD) {
        const int d = nD * 16 + r15;
        const int b0 = (hh * 8 + lh) ^ r15;
        const int b1 = (hh * 8 + 4 + lh) ^ r15;
        bf16x8 vf0 = *(const bf16x8*)(Vls + d * 128 + b0 * 8);
        bf16x8 vf1 = *(const bf16x8*)(Vls + d * 128 + b1 * 8);
        o_acc[nD] = __builtin_amdgcn_mfma_f32_16x16x32_bf16(vf0, pa0, o_acc[nD], 0, 0, 0);
        o_acc[nD] = __builtin_amdgcn_mfma_f32_16x16x32_bf16(vf1, pa1, o_acc[nD], 0, 0, 0);
      }
      __builtin_amdgcn_s_setprio(0);
    };

    // ---- chain A scores (on last tile, upper half of A is fully masked) ----
    {
      f32x4 sfA[8];
      __builtin_amdgcn_s_setprio(1);
#pragma unroll
      for (int n = 0; n < 4; ++n) qk_n(qfA, n, sfA);
      __builtin_amdgcn_s_setprio(0);
      if (!last) {
        __builtin_amdgcn_s_setprio(1);
#pragma unroll
        for (int n = 4; n < 8; ++n) qk_n(qfA, n, sfA);
        __builtin_amdgcn_s_setprio(0);
      }
      sm_half(sfA, 0, PA, qrowA, last, l_A);
      if (!last) sm_half(sfA, 1, PB, qrowA, false, l_A);
    }

    // ---- chain B scores (B0 never masked; B1 masked on last) ----
    f32x4 sfB[8];
    __builtin_amdgcn_s_setprio(1);
#pragma unroll
    for (int n = 0; n < 8; ++n) qk_n(qfB, n, sfB);
    __builtin_amdgcn_s_setprio(0);

    WAITVM(0);                        // own V(t) drained (issued last iter)
    __builtin_amdgcn_s_barrier();     // K(t) consumed by all; V(t) visible
    if (more) stage_k128(Kg, Kls, kv0 + 128, w, l);

    // ---- PV(A) ∥ sm(B) braid ----
    pv_half(0, PA, oA);
    if (!last) pv_half(1, PB, oA);
    sm_half(sfB, 0, PA, qrowB, false, l_B);
    sm_half(sfB, 1, PB, qrowB, last, l_B);
    pv_half(0, PA, oB);
    pv_half(1, PB, oB);

    if (more) {
      WAITVM(0);                      // own K(t+1) drained
      __builtin_amdgcn_s_barrier();   // V(t) consumed; K(t+1) visible to all
      stage_v128(Vg, Vls, kv0 + 128, w, l);   // flies into next tile
    }
  }

  // ---- epilogues ----
  {
    float ls = l_A;
    ls += __shfl_xor(ls, 16, 64);
    ls += __shfl_xor(ls, 32, 64);
    const float invl = 1.f / ls;
    bf16_t* orow = Om + (size_t)(b * T_SEQ + qrowA) * D_MODEL + h * 64;
#pragma unroll
    for (int n = 0; n < 4; ++n) {
      bf16x4 pk = { (bf16_t)(oA[n][0] * invl), (bf16_t)(oA[n][1] * invl),
                    (bf16_t)(oA[n][2] * invl), (bf16_t)(oA[n][3] * invl) };
      *(bf16x4*)(orow + n * 16 + lh * 4) = pk;
    }
  }
  {
    float ls = l_B;
    ls += __shfl_xor(ls, 16, 64);
    ls += __shfl_xor(ls, 32, 64);
    const float invl = 1.f / ls;
    bf16_t* orow = Om + (size_t)(b * T_SEQ + qrowB) * D_MODEL + h * 64;
#pragma unroll
    for (int n = 0; n < 4; ++n) {
      bf16x4 pk = { (bf16_t)(oB[n][0] * invl), (bf16_t)(oB[n][1] * invl),
                    (bf16_t)(oB[n][2] * invl), (bf16_t)(oB[n][3] * invl) };
      *(bf16x4*)(orow + n * 16 + lh * 4) = pk;
    }
  }
}

// ---------------- host launch ----------------
extern "C" void kernel_launch(void* const* d_in, const int* in_sizes, int n_in,
                              void* d_out, int out_size, void* d_ws, size_t ws_size,
                              hipStream_t stream) {
  const float* x  = (const float*)d_in[0];
  const float* wq = (const float*)d_in[1];
  const float* bq = (const float*)d_in[2];
  const float* wk = (const float*)d_in[3];
  const float* bk = (const float*)d_in[4];
  const float* wv = (const float*)d_in[5];
  const float* bv = (const float*)d_in[6];
  const float* wo = (const float*)d_in[7];
  const float* bo = (const float*)d_in[8];

  char* ws = (char*)d_ws;
  const size_t MB = 1024 * 1024;
  bf16_t* xb  = (bf16_t*)(ws);
  bf16_t* wqb = (bf16_t*)(ws + 8 * MB);
  bf16_t* wkb = (bf16_t*)(ws + 10 * MB);
  bf16_t* wvb = (bf16_t*)(ws + 12 * MB);
  bf16_t* wob = (bf16_t*)(ws + 14 * MB);
  bf16_t* qb  = (bf16_t*)(ws + 16 * MB);
  bf16_t* kb  = (bf16_t*)(ws + 24 * MB);
  bf16_t* vtb = (bf16_t*)(ws + 32 * MB);  // V^T [B][1024][2048]
  bf16_t* ob  = (bf16_t*)(ws + 40 * MB);

  CastArgs ca;
  ca.src[0] = x;  ca.dst[0] = xb;
  ca.src[1] = wq; ca.dst[1] = wqb;
  ca.src[2] = wk; ca.dst[2] = wkb;
  ca.src[3] = wv; ca.dst[3] = wvb;
  ca.src[4] = wo; ca.dst[4] = wob;
  cast_all<<<8192, 256, 0, stream>>>(ca);

  QKVArgs qa;
  qa.A = xb;
  qa.W[0] = wqb; qa.W[1] = wkb; qa.W[2] = wvb;
  qa.bias[0] = bq; qa.bias[1] = bk; qa.bias[2] = bv;
  qa.out[0] = qb; qa.out[1] = kb; qa.out[2] = vtb;
  qkv_gemm<<<256, 512, 0, stream>>>(qa);

  flash_attn<<<512, 256, 0, stream>>>(qb, kb, vtb, ob);

  out_gemm<<<dim3(64, 8), 256, 0, stream>>>(ob, wob, bo, (float*)d_out);
}

// Round 13
// 97.989 us; speedup vs baseline: 1.0431x; 1.0315x over previous
//
#include <hip/hip_runtime.h>
#include <hip/hip_bf16.h>

typedef __bf16 bf16_t;
typedef __bf16 bf16x8 __attribute__((ext_vector_type(8)));
typedef __bf16 bf16x4 __attribute__((ext_vector_type(4)));
typedef float f32x4 __attribute__((ext_vector_type(4)));
typedef unsigned int u32;

#define D_MODEL 1024
#define T_SEQ   2048
#define N_HEADS 16

#define WAITVM(N) asm volatile("s_waitcnt vmcnt(" #N ")" ::: "memory")

__device__ __forceinline__ void gload_lds16(const void* g, void* l) {
  __builtin_amdgcn_global_load_lds((const __attribute__((address_space(1))) u32*)g,
                                   (__attribute__((address_space(3))) u32*)l, 16, 0, 0);
}

__device__ __forceinline__ float fast_exp2(float x) {
#if __has_builtin(__builtin_amdgcn_exp2f)
  return __builtin_amdgcn_exp2f(x);
#else
  return __expf(x * 0.69314718056f);
#endif
}

// ---------------- fused fp32->bf16 cast (x + 4 weights) ----------------
struct CastArgs { const float* src[5]; bf16_t* dst[5]; };

__global__ __launch_bounds__(256) void cast_all(CastArgs p) {
  unsigned i = (blockIdx.x * 256u + threadIdx.x) * 4u;
  int seg; unsigned off;
  if (i < 4194304u) { seg = 0; off = i; }
  else { unsigned r = i - 4194304u; seg = 1 + (int)(r >> 20); off = r & 1048575u; }
  const float4 v = *(const float4*)(p.src[seg] + off);
  bf16x4 o = { (bf16_t)v.x, (bf16_t)v.y, (bf16_t)v.z, (bf16_t)v.w };
  *(bf16x4*)(p.dst[seg] + off) = o;
}

#define QSCL 0.18033688011112042f   // 0.125 * log2(e)

// ============== fused QKV: 256x192 tile, BK=64, 4-phase, 512 thr ==============
// All next-tile staging issued at phase 0 so the phase-3 vmcnt(0) drain has
// three phases of latency cover.
struct QKVArgs {
  const bf16_t* A;
  const bf16_t* W[3];
  const float* bias[3];
  bf16_t* out[3];
};

__global__ __launch_bounds__(512, 2) void qkv_gemm(QKVArgs p) {
  __shared__ bf16_t lds[2 * 28672];   // [buf][A:16384 | B:12288]

  const int tid = threadIdx.x;
  const int l = tid & 63, wid = tid >> 6;
  const int lh = l >> 4, r15 = l & 15;

  const int lid = blockIdx.x;
  const int bx = lid >> 4, by = lid & 15;
  const int brow = bx * 256;
  const int gcol0 = by * 192;

  const int wr = (wid >> 2) * 128;
  const int wc = (wid & 3) * 48;
  const int wrc = (wr >> 4);
  const int wcc = (wc >> 4);
  const int sA = (lh ^ ((r15 >> 1) & 3)) * 8;
  const int roff = r15 * 32;

  const int srow = l >> 2;
  const int gs = ((l & 3) ^ ((l >> 3) & 3)) * 8;

  f32x4 acc[8][3];
  const f32x4 zero = {0.f, 0.f, 0.f, 0.f};
#pragma unroll
  for (int i = 0; i < 8; ++i)
#pragma unroll
    for (int j = 0; j < 3; ++j) acc[i][j] = zero;

  const bf16_t* A = p.A;

  auto stageA = [&](bf16_t* buf, int k0, int kh) {
#pragma unroll
    for (int i = 0; i < 2; ++i) {
      int c = wid * 2 + i;
      gload_lds16(A + (size_t)(brow + c * 16 + srow) * D_MODEL + k0 + kh * 32 + gs,
                  buf + kh * 8192 + c * 512);
    }
  };
  auto stageB = [&](bf16_t* buf, int k0) {
#pragma unroll
    for (int i = 0; i < 3; ++i) {
      int g = wid * 3 + i;
      int kh = g >= 12;
      int c = g - kh * 12;
      int gcol = gcol0 + c * 16 + srow;
      int z = gcol >> 10;
      const bf16_t* w = (z == 0) ? p.W[0] : ((z == 1) ? p.W[1] : p.W[2]);
      gload_lds16(w + (size_t)(gcol & 1023) * D_MODEL + k0 + kh * 32 + gs,
                  buf + 16384 + kh * 6144 + c * 512);
    }
  };

  stageA(lds, 0, 0);
  stageA(lds, 0, 1);
  stageB(lds, 0);
  WAITVM(0);
  __builtin_amdgcn_s_barrier();

  for (int t = 0; t < 16; ++t) {
    bf16_t* cur = lds + (t & 1) * 28672;
    bf16_t* nxt = lds + ((t + 1) & 1) * 28672;
    const int k1 = (t + 1) * 64;
    const bool more = (t < 15);

    bf16x8 bfr[3][2];
#pragma unroll
    for (int ph = 0; ph < 4; ++ph) {
      bf16x8 a[2][2];
#pragma unroll
      for (int jj = 0; jj < 2; ++jj)
#pragma unroll
        for (int kh = 0; kh < 2; ++kh)
          a[jj][kh] = *(const bf16x8*)(cur + kh * 8192 + (wrc + 2 * ph + jj) * 512 + roff + sA);
      if (ph == 0) {
#pragma unroll
        for (int ni = 0; ni < 3; ++ni)
#pragma unroll
          for (int kh = 0; kh < 2; ++kh)
            bfr[ni][kh] = *(const bf16x8*)(cur + 16384 + kh * 6144 + (wcc + ni) * 512 + roff + sA);
        if (more) {                     // issue ALL next-tile staging here
          stageA(nxt, k1, 0);
          stageA(nxt, k1, 1);
          stageB(nxt, k1);
        }
      }
      __builtin_amdgcn_s_barrier();
      __builtin_amdgcn_s_setprio(1);
#pragma unroll
      for (int jj = 0; jj < 2; ++jj)
#pragma unroll
        for (int ni = 0; ni < 3; ++ni) {
          acc[2 * ph + jj][ni] = __builtin_amdgcn_mfma_f32_16x16x32_bf16(a[jj][0], bfr[ni][0], acc[2 * ph + jj][ni], 0, 0, 0);
          acc[2 * ph + jj][ni] = __builtin_amdgcn_mfma_f32_16x16x32_bf16(a[jj][1], bfr[ni][1], acc[2 * ph + jj][ni], 0, 0, 0);
        }
      __builtin_amdgcn_s_setprio(0);
      if (ph == 3 && more) WAITVM(0);
      __builtin_amdgcn_s_barrier();
    }
  }

#pragma unroll
  for (int ni = 0; ni < 3; ++ni) {
    const int col = gcol0 + wc + ni * 16 + r15;
    const int z = col >> 10;
    const int zc = col & 1023;
    const float* bias = (z == 0) ? p.bias[0] : ((z == 1) ? p.bias[1] : p.bias[2]);
    bf16_t* O = (z == 0) ? p.out[0] : ((z == 1) ? p.out[1] : p.out[2]);
    const float bz = bias[zc];
    if (z == 2) {
#pragma unroll
      for (int mi = 0; mi < 8; ++mi) {
        int row0 = brow + wr + mi * 16 + lh * 4;
        int bb = row0 >> 11, t0 = row0 & 2047;
        bf16x4 pk;
#pragma unroll
        for (int j = 0; j < 4; ++j) pk[j] = (bf16_t)(acc[mi][ni][j] + bz);
        *(bf16x4*)(O + (size_t)bb * (D_MODEL * T_SEQ) + (size_t)zc * T_SEQ + t0) = pk;
      }
    } else if (z == 0) {
#pragma unroll
      for (int mi = 0; mi < 8; ++mi) {
        int row0 = brow + wr + mi * 16 + lh * 4;
#pragma unroll
        for (int j = 0; j < 4; ++j)
          O[(size_t)(row0 + j) * D_MODEL + zc] = (bf16_t)((acc[mi][ni][j] + bz) * QSCL);
      }
    } else {
#pragma unroll
      for (int mi = 0; mi < 8; ++mi) {
        int row0 = brow + wr + mi * 16 + lh * 4;
#pragma unroll
        for (int j = 0; j < 4; ++j)
          O[(size_t)(row0 + j) * D_MODEL + zc] = (bf16_t)(acc[mi][ni][j] + bz);
      }
    }
  }
}

// ---------------- 64x128 GEMM (out projection) ----------------
__device__ __forceinline__ void stage_ab64(
    const bf16_t* __restrict__ A, const bf16_t* __restrict__ W,
    bf16_t* buf, int brow, int bcol, int k0, int w, int l) {
  const int srow = l >> 2;
  const int scol = ((l & 3) ^ ((l >> 3) & 3)) * 8;
#pragma unroll
  for (int i = 0; i < 3; ++i) {
    int ch = w * 3 + i;
    const bf16_t* src = (ch < 4)
      ? A + (size_t)(brow + ch * 16 + srow) * D_MODEL + k0 + scol
      : W + (size_t)(bcol + (ch - 4) * 16 + srow) * D_MODEL + k0 + scol;
    gload_lds16(src, buf + ch * 512);
  }
}

__device__ __forceinline__ void gemm_tile_64(
    const bf16_t* __restrict__ A, const bf16_t* __restrict__ W,
    bf16_t* bufs, int brow, int bcol, f32x4 acc[2][4])
{
  const int tid = threadIdx.x;
  const int l = tid & 63, w = tid >> 6;
  const int wr = (w >> 1) * 32, wc = (w & 1) * 64;
  const int lh = l >> 4, r15 = l & 15;
  const int NS = D_MODEL / 32;

  stage_ab64(A, W, bufs + 0 * 6144, brow, bcol, 0, w, l);
  stage_ab64(A, W, bufs + 1 * 6144, brow, bcol, 32, w, l);

  for (int t = 0; t < NS; ++t) {
    bf16_t* bb = bufs + (t % 3) * 6144;
    if (t + 2 < NS) {
      stage_ab64(A, W, bufs + ((t + 2) % 3) * 6144, brow, bcol, (t + 2) * 32, w, l);
      WAITVM(6);
    } else if (t + 1 < NS) {
      WAITVM(3);
    } else {
      WAITVM(0);
    }
    __builtin_amdgcn_s_barrier();

    bf16x8 af[2], bfr[4];
#pragma unroll
    for (int mi = 0; mi < 2; ++mi) {
      int rr = wr + mi * 16 + r15;
      int s = lh ^ ((rr >> 1) & 3);
      af[mi] = *(const bf16x8*)(bb + rr * 32 + s * 8);
    }
#pragma unroll
    for (int ni = 0; ni < 4; ++ni) {
      int rr = wc + ni * 16 + r15;
      int s = lh ^ ((rr >> 1) & 3);
      bfr[ni] = *(const bf16x8*)(bb + 2048 + rr * 32 + s * 8);
    }
    __builtin_amdgcn_s_setprio(1);
#pragma unroll
    for (int mi = 0; mi < 2; ++mi)
#pragma unroll
      for (int ni = 0; ni < 4; ++ni)
        acc[mi][ni] = __builtin_amdgcn_mfma_f32_16x16x32_bf16(af[mi], bfr[ni], acc[mi][ni], 0, 0, 0);
    __builtin_amdgcn_s_setprio(0);
    __builtin_amdgcn_s_barrier();
  }
}

__global__ __launch_bounds__(256) void out_gemm(
    const bf16_t* __restrict__ A, const bf16_t* __restrict__ W,
    const float* __restrict__ bias, float* __restrict__ O)
{
  __shared__ bf16_t bufs[3 * 6144];
  f32x4 acc[2][4];
  f32x4 zero = {0.f, 0.f, 0.f, 0.f};
#pragma unroll
  for (int i = 0; i < 2; ++i)
#pragma unroll
    for (int j = 0; j < 4; ++j) acc[i][j] = zero;

  const int brow = blockIdx.x * 64, bcol = blockIdx.y * 128;
  gemm_tile_64(A, W, bufs, brow, bcol, acc);

  const int tid = threadIdx.x, l = tid & 63, w = tid >> 6;
  const int wr = (w >> 1) * 32, wc = (w & 1) * 64, lh = l >> 4, r15 = l & 15;
#pragma unroll
  for (int ni = 0; ni < 4; ++ni) {
    int col = bcol + wc + ni * 16 + r15;
    float bz = bias[col];
#pragma unroll
    for (int mi = 0; mi < 2; ++mi) {
      int row0 = brow + wr + mi * 16 + lh * 4;
#pragma unroll
      for (int j = 0; j < 4; ++j)
        O[(size_t)(row0 + j) * D_MODEL + col] = acc[mi][ni][j] + bz;
    }
  }
}

// ---------------- causal flash attention: unfolded, KVBLK=128, 40KB LDS ------
// 1024 blocks: qt = 31-(lid>>5) (LPT), bh = lid&31 (head pinned to one XCD).
// One 64-row q-tile per block, (qt>>1)+1 kv-tiles of 128. K,V single-buffered
// with sound drain+barrier handshakes; P = single per-wave 16x64 XOR-swizzled
// buffer reused by both 64-kv halves (wave-ordered DS ops make WAR safe).
// LDS = 16K (K) + 16K (V) + 8K (P) = 40960 -> 4 blocks/CU resident.
__device__ __forceinline__ void stage_k128(const bf16_t* Kg, bf16_t* Kd, int kv0, int w, int l) {
#pragma unroll
  for (int i = 0; i < 4; ++i) {
    int c = w * 4 + i;
    int row = c * 8 + (l >> 3);
    int gcol = ((l & 7) ^ ((l >> 3) & 7)) * 8;
    gload_lds16(Kg + (size_t)(kv0 + row) * D_MODEL + gcol, Kd + c * 512);
  }
}
__device__ __forceinline__ void stage_v128(const bf16_t* Vg, bf16_t* Vd, int kv0, int w, int l) {
#pragma unroll
  for (int i = 0; i < 4; ++i) {
    int c = w * 4 + i;
    int drow = c * 4 + (l >> 4);
    int gkv = ((l & 15) ^ (drow & 15)) * 8;
    gload_lds16(Vg + (size_t)drow * T_SEQ + kv0 + gkv, Vd + c * 512);
  }
}

__global__ __launch_bounds__(256) void flash_attn(
    const bf16_t* __restrict__ Qm, const bf16_t* __restrict__ Km,
    const bf16_t* __restrict__ Vtg, bf16_t* __restrict__ Om)
{
  __shared__ bf16_t Kls[128 * 64];
  __shared__ bf16_t Vls[64 * 128];
  __shared__ bf16_t Pls[4][16 * 64];

  const int tid = threadIdx.x, l = tid & 63, w = tid >> 6;
  const int lh = l >> 4, r15 = l & 15;

  const int lid = blockIdx.x;
  const int qt = 31 - (lid >> 5);       // big q-tiles dispatch first (LPT)
  const int bh = lid & 31;              // head pinned to one XCD
  const int b = bh >> 4, h = bh & 15;
  const int nT = (qt >> 1) + 1;

  const size_t baseQ = (size_t)b * T_SEQ * D_MODEL + h * 64;
  const size_t baseVt = (size_t)b * (D_MODEL * T_SEQ) + (size_t)(h * 64) * T_SEQ;
  const bf16_t* Kg = Km + baseQ;
  const bf16_t* Vg = Vtg + baseVt;

  const int qw = qt * 64 + w * 16;
  const int qrow = qw + r15;
  const int sw7 = r15 & 7;

  bf16x8 qf[2];
  {
    const bf16_t* qp = Qm + baseQ + (size_t)qrow * D_MODEL + lh * 8;
    qf[0] = *(const bf16x8*)(qp);
    qf[1] = *(const bf16x8*)(qp + 32);
  }

  float l_r = 0.f;
  f32x4 o_acc[4];
  const f32x4 zero = {0.f, 0.f, 0.f, 0.f};
#pragma unroll
  for (int n = 0; n < 4; ++n) o_acc[n] = zero;

  bf16_t* P = &Pls[w][0];

  stage_k128(Kg, Kls, 0, w, l);
  stage_v128(Vg, Vls, 0, w, l);
  WAITVM(0);
  __builtin_amdgcn_s_barrier();

  for (int t = 0; t < nT; ++t) {
    const int kv0 = t * 128;
    const bool more = (t + 1 < nT);
    const bool diag = (t == nT - 1);
    const bool skip2 = diag && ((qt & 1) == 0);

    // ---- S^T = K Q^T ----
    f32x4 sf[8];
    auto qk_n = [&](int n) {
      const int kvc = n * 16 + r15;
      const int sw = kvc & 7;
      bf16x8 kf0 = *(const bf16x8*)(Kls + kvc * 64 + ((lh ^ sw) * 8));
      bf16x8 kf1 = *(const bf16x8*)(Kls + kvc * 64 + (((4 + lh) ^ sw) * 8));
      f32x4 a = zero;
      a = __builtin_amdgcn_mfma_f32_16x16x32_bf16(kf0, qf[0], a, 0, 0, 0);
      a = __builtin_amdgcn_mfma_f32_16x16x32_bf16(kf1, qf[1], a, 0, 0, 0);
      sf[n] = a;
    };
    __builtin_amdgcn_s_setprio(1);
#pragma unroll
    for (int n = 0; n < 4; ++n) qk_n(n);
    __builtin_amdgcn_s_setprio(0);
    if (!skip2) {
      __builtin_amdgcn_s_setprio(1);
#pragma unroll
      for (int n = 4; n < 8; ++n) qk_n(n);
      __builtin_amdgcn_s_setprio(0);
    }

    WAITVM(0);                           // drain own V(t) (issued end of t-1)
    __builtin_amdgcn_s_barrier();        // all K reads done; all V(t) landed
    if (more) stage_k128(Kg, Kls, kv0 + 128, w, l);

    // ---- softmax half -> P (XOR-swizzled), then PV; P reused across halves ----
    auto sm_half = [&](int hh, bool dm) {
#pragma unroll
      for (int n2 = 0; n2 < 4; ++n2) {
        const int n = hh * 4 + n2;
        float pv[4];
#pragma unroll
        for (int j = 0; j < 4; ++j) {
          float pp = fast_exp2(sf[n][j]);
          if (dm) {
            const int kvcol = kv0 + hh * 64 + n2 * 16 + lh * 4 + j;
            if (kvcol > qrow) pp = 0.f;
          }
          pv[j] = pp;
          l_r += pp;
        }
        bf16x4 pk = { (bf16_t)pv[0], (bf16_t)pv[1], (bf16_t)pv[2], (bf16_t)pv[3] };
        const int slot = n2 * 2 + (lh >> 1);
        *(bf16x4*)(P + r15 * 64 + ((slot ^ sw7) * 8) + (lh & 1) * 4) = pk;
      }
    };
    auto pv_half = [&](int hh) {
      bf16x8 pa0 = *(const bf16x8*)(P + r15 * 64 + ((lh ^ sw7) * 8));
      bf16x8 pa1 = *(const bf16x8*)(P + r15 * 64 + (((4 + lh) ^ sw7) * 8));
      __builtin_amdgcn_s_setprio(1);
#pragma unroll
      for (int nD = 0; nD < 4; ++nD) {
        const int d = nD * 16 + r15;
        const int b0 = (hh * 8 + lh) ^ r15;
        const int b1 = (hh * 8 + 4 + lh) ^ r15;
        bf16x8 vf0 = *(const bf16x8*)(Vls + d * 128 + b0 * 8);
        bf16x8 vf1 = *(const bf16x8*)(Vls + d * 128 + b1 * 8);
        o_acc[nD] = __builtin_amdgcn_mfma_f32_16x16x32_bf16(vf0, pa0, o_acc[nD], 0, 0, 0);
        o_acc[nD] = __builtin_amdgcn_mfma_f32_16x16x32_bf16(vf1, pa1, o_acc[nD], 0, 0, 0);
      }
      __builtin_amdgcn_s_setprio(0);
    };

    sm_half(0, diag);
    pv_half(0);
    if (!skip2) {
      sm_half(1, diag);                  // WAR on P is safe: wave DS ops in order
      pv_half(1);
    }

    WAITVM(0);                           // drain own K(t+1) (issued mid-tile)
    __builtin_amdgcn_s_barrier();        // all V reads done; K(t+1) landed
    if (more) stage_v128(Vg, Vls, kv0 + 128, w, l);   // flies into next tile
  }

  // ---- epilogue ----
  float ls = l_r;
  ls += __shfl_xor(ls, 16, 64);
  ls += __shfl_xor(ls, 32, 64);
  const float invl = 1.f / ls;
  bf16_t* orow = Om + (size_t)(b * T_SEQ + qrow) * D_MODEL + h * 64;
#pragma unroll
  for (int n = 0; n < 4; ++n) {
    bf16x4 pk = { (bf16_t)(o_acc[n][0] * invl), (bf16_t)(o_acc[n][1] * invl),
                  (bf16_t)(o_acc[n][2] * invl), (bf16_t)(o_acc[n][3] * invl) };
    *(bf16x4*)(orow + n * 16 + lh * 4) = pk;
  }
}

// ---------------- host launch ----------------
extern "C" void kernel_launch(void* const* d_in, const int* in_sizes, int n_in,
                              void* d_out, int out_size, void* d_ws, size_t ws_size,
                              hipStream_t stream) {
  const float* x  = (const float*)d_in[0];
  const float* wq = (const float*)d_in[1];
  const float* bq = (const float*)d_in[2];
  const float* wk = (const float*)d_in[3];
  const float* bk = (const float*)d_in[4];
  const float* wv = (const float*)d_in[5];
  const float* bv = (const float*)d_in[6];
  const float* wo = (const float*)d_in[7];
  const float* bo = (const float*)d_in[8];

  char* ws = (char*)d_ws;
  const size_t MB = 1024 * 1024;
  bf16_t* xb  = (bf16_t*)(ws);
  bf16_t* wqb = (bf16_t*)(ws + 8 * MB);
  bf16_t* wkb = (bf16_t*)(ws + 10 * MB);
  bf16_t* wvb = (bf16_t*)(ws + 12 * MB);
  bf16_t* wob = (bf16_t*)(ws + 14 * MB);
  bf16_t* qb  = (bf16_t*)(ws + 16 * MB);
  bf16_t* kb  = (bf16_t*)(ws + 24 * MB);
  bf16_t* vtb = (bf16_t*)(ws + 32 * MB);  // V^T [B][1024][2048]
  bf16_t* ob  = (bf16_t*)(ws + 40 * MB);

  CastArgs ca;
  ca.src[0] = x;  ca.dst[0] = xb;
  ca.src[1] = wq; ca.dst[1] = wqb;
  ca.src[2] = wk; ca.dst[2] = wkb;
  ca.src[3] = wv; ca.dst[3] = wvb;
  ca.src[4] = wo; ca.dst[4] = wob;
  cast_all<<<8192, 256, 0, stream>>>(ca);

  QKVArgs qa;
  qa.A = xb;
  qa.W[0] = wqb; qa.W[1] = wkb; qa.W[2] = wvb;
  qa.bias[0] = bq; qa.bias[1] = bk; qa.bias[2] = bv;
  qa.out[0] = qb; qa.out[1] = kb; qa.out[2] = vtb;
  qkv_gemm<<<256, 512, 0, stream>>>(qa);

  flash_attn<<<1024, 256, 0, stream>>>(qb, kb, vtb, ob);

  out_gemm<<<dim3(64, 8), 256, 0, stream>>>(ob, wob, bo, (float*)d_out);
}

// Round 14
// 91.118 us; speedup vs baseline: 1.1217x; 1.0754x over previous
//
#include <hip/hip_runtime.h>
#include <hip/hip_bf16.h>

typedef __bf16 bf16_t;
typedef __bf16 bf16x8 __attribute__((ext_vector_type(8)));
typedef __bf16 bf16x4 __attribute__((ext_vector_type(4)));
typedef float f32x4 __attribute__((ext_vector_type(4)));
typedef unsigned int u32;

#define D_MODEL 1024
#define T_SEQ   2048
#define N_HEADS 16

#define WAITVM(N) asm volatile("s_waitcnt vmcnt(" #N ")" ::: "memory")

__device__ __forceinline__ void gload_lds16(const void* g, void* l) {
  __builtin_amdgcn_global_load_lds((const __attribute__((address_space(1))) u32*)g,
                                   (__attribute__((address_space(3))) u32*)l, 16, 0, 0);
}

__device__ __forceinline__ float fast_exp2(float x) {
#if __has_builtin(__builtin_amdgcn_exp2f)
  return __builtin_amdgcn_exp2f(x);
#else
  return __expf(x * 0.69314718056f);
#endif
}

// ---------------- fused fp32->bf16 cast (x + 4 weights) ----------------
struct CastArgs { const float* src[5]; bf16_t* dst[5]; };

__global__ __launch_bounds__(256) void cast_all(CastArgs p) {
  unsigned i = (blockIdx.x * 256u + threadIdx.x) * 4u;
  int seg; unsigned off;
  if (i < 4194304u) { seg = 0; off = i; }
  else { unsigned r = i - 4194304u; seg = 1 + (int)(r >> 20); off = r & 1048575u; }
  const float4 v = *(const float4*)(p.src[seg] + off);
  bf16x4 o = { (bf16_t)v.x, (bf16_t)v.y, (bf16_t)v.z, (bf16_t)v.w };
  *(bf16x4*)(p.dst[seg] + off) = o;
}

#define QSCL 0.18033688011112042f   // 0.125 * log2(e)

// ============== fused QKV: 128x192 tile, BK=64, 256 thr, 2 blocks/CU =========
// One barrier per K-tile; vmcnt(0) drain pre-covered by a full tile of compute
// (loads issued one tile ahead). LDS = 2 x 40KB = 80KB -> 2 resident/CU.
// Grid 512: by = lid&15 (shared B panel for lid & lid+256), bx = lid>>4.
struct QKVArgs {
  const bf16_t* A;
  const bf16_t* W[3];
  const float* bias[3];
  bf16_t* out[3];
};

__global__ __launch_bounds__(256, 2) void qkv_gemm(QKVArgs p) {
  __shared__ bf16_t lds[2 * 20480];   // [buf][A:8192 | B:12288] elems

  const int tid = threadIdx.x;
  const int l = tid & 63, w = tid >> 6;
  const int lh = l >> 4, r15 = l & 15;

  const int lid = blockIdx.x;
  const int by = lid & 15, bx = lid >> 4;
  const int brow = bx * 128;
  const int gcol0 = by * 192;

  const int wr = (w >> 1) * 64;        // 2 M-warps x 64 rows
  const int wc = (w & 1) * 96;         // 2 N-warps x 96 cols
  const int wrc = wr >> 4;             // A row-chunk base (0 or 4)
  const int wcc = wc >> 4;             // B col-chunk base (0 or 6)
  const int sA = (lh ^ ((r15 >> 1) & 3)) * 8;
  const int roff = r15 * 32;

  const int srow = l >> 2;
  const int gs = ((l & 3) ^ ((l >> 3) & 3)) * 8;

  f32x4 acc[4][6];
  const f32x4 zero = {0.f, 0.f, 0.f, 0.f};
#pragma unroll
  for (int i = 0; i < 4; ++i)
#pragma unroll
    for (int j = 0; j < 6; ++j) acc[i][j] = zero;

  const bf16_t* A = p.A;

  auto stage = [&](bf16_t* buf, int k0) {
#pragma unroll
    for (int i = 0; i < 4; ++i) {           // A: 16 chunk-units (kh*8+cc)
      int c = w * 4 + i;
      int kh = c >> 3, cc = c & 7;
      gload_lds16(A + (size_t)(brow + cc * 16 + srow) * D_MODEL + k0 + kh * 32 + gs,
                  buf + c * 512);
    }
#pragma unroll
    for (int i = 0; i < 6; ++i) {           // B: 24 chunk-units (kh*12+cb)
      int g = w * 6 + i;
      int kh = g >= 12;
      int cb = g - kh * 12;
      int gcol = gcol0 + cb * 16 + srow;
      int z = gcol >> 10;
      const bf16_t* wt = (z == 0) ? p.W[0] : ((z == 1) ? p.W[1] : p.W[2]);
      gload_lds16(wt + (size_t)(gcol & 1023) * D_MODEL + k0 + kh * 32 + gs,
                  buf + 8192 + g * 512);
    }
  };

  stage(lds, 0);                            // tile 0

  for (int t = 0; t < 16; ++t) {
    bf16_t* cur = lds + (t & 1) * 20480;
    WAITVM(0);                              // tile-t loads (issued a tile ago)
    __builtin_amdgcn_s_barrier();           // all waves' loads landed; t-1 done
    if (t < 15) stage(lds + ((t + 1) & 1) * 20480, (t + 1) * 64);

#pragma unroll
    for (int kh = 0; kh < 2; ++kh) {
      bf16x8 bfr[6];
#pragma unroll
      for (int ni = 0; ni < 6; ++ni)
        bfr[ni] = *(const bf16x8*)(cur + 8192 + (kh * 12 + wcc + ni) * 512 + roff + sA);
      __builtin_amdgcn_s_setprio(1);
#pragma unroll
      for (int mi = 0; mi < 4; ++mi) {
        bf16x8 af = *(const bf16x8*)(cur + (kh * 8 + wrc + mi) * 512 + roff + sA);
#pragma unroll
        for (int ni = 0; ni < 6; ++ni)
          acc[mi][ni] = __builtin_amdgcn_mfma_f32_16x16x32_bf16(af, bfr[ni], acc[mi][ni], 0, 0, 0);
      }
      __builtin_amdgcn_s_setprio(0);
    }
  }

  // ---- epilogue ----
#pragma unroll
  for (int ni = 0; ni < 6; ++ni) {
    const int col = gcol0 + wc + ni * 16 + r15;
    const int z = col >> 10;
    const int zc = col & 1023;
    const float* bias = (z == 0) ? p.bias[0] : ((z == 1) ? p.bias[1] : p.bias[2]);
    bf16_t* O = (z == 0) ? p.out[0] : ((z == 1) ? p.out[1] : p.out[2]);
    const float bz = bias[zc];
    if (z == 2) {
#pragma unroll
      for (int mi = 0; mi < 4; ++mi) {
        int row0 = brow + wr + mi * 16 + lh * 4;
        int bb = row0 >> 11, t0 = row0 & 2047;
        bf16x4 pk;
#pragma unroll
        for (int j = 0; j < 4; ++j) pk[j] = (bf16_t)(acc[mi][ni][j] + bz);
        *(bf16x4*)(O + (size_t)bb * (D_MODEL * T_SEQ) + (size_t)zc * T_SEQ + t0) = pk;
      }
    } else if (z == 0) {
#pragma unroll
      for (int mi = 0; mi < 4; ++mi) {
        int row0 = brow + wr + mi * 16 + lh * 4;
#pragma unroll
        for (int j = 0; j < 4; ++j)
          O[(size_t)(row0 + j) * D_MODEL + zc] = (bf16_t)((acc[mi][ni][j] + bz) * QSCL);
      }
    } else {
#pragma unroll
      for (int mi = 0; mi < 4; ++mi) {
        int row0 = brow + wr + mi * 16 + lh * 4;
#pragma unroll
        for (int j = 0; j < 4; ++j)
          O[(size_t)(row0 + j) * D_MODEL + zc] = (bf16_t)(acc[mi][ni][j] + bz);
      }
    }
  }
}

// ---------------- 64x128 GEMM (out projection) ----------------
__device__ __forceinline__ void stage_ab64(
    const bf16_t* __restrict__ A, const bf16_t* __restrict__ W,
    bf16_t* buf, int brow, int bcol, int k0, int w, int l) {
  const int srow = l >> 2;
  const int scol = ((l & 3) ^ ((l >> 3) & 3)) * 8;
#pragma unroll
  for (int i = 0; i < 3; ++i) {
    int ch = w * 3 + i;
    const bf16_t* src = (ch < 4)
      ? A + (size_t)(brow + ch * 16 + srow) * D_MODEL + k0 + scol
      : W + (size_t)(bcol + (ch - 4) * 16 + srow) * D_MODEL + k0 + scol;
    gload_lds16(src, buf + ch * 512);
  }
}

__device__ __forceinline__ void gemm_tile_64(
    const bf16_t* __restrict__ A, const bf16_t* __restrict__ W,
    bf16_t* bufs, int brow, int bcol, f32x4 acc[2][4])
{
  const int tid = threadIdx.x;
  const int l = tid & 63, w = tid >> 6;
  const int wr = (w >> 1) * 32, wc = (w & 1) * 64;
  const int lh = l >> 4, r15 = l & 15;
  const int NS = D_MODEL / 32;

  stage_ab64(A, W, bufs + 0 * 6144, brow, bcol, 0, w, l);
  stage_ab64(A, W, bufs + 1 * 6144, brow, bcol, 32, w, l);

  for (int t = 0; t < NS; ++t) {
    bf16_t* bb = bufs + (t % 3) * 6144;
    if (t + 2 < NS) {
      stage_ab64(A, W, bufs + ((t + 2) % 3) * 6144, brow, bcol, (t + 2) * 32, w, l);
      WAITVM(6);
    } else if (t + 1 < NS) {
      WAITVM(3);
    } else {
      WAITVM(0);
    }
    __builtin_amdgcn_s_barrier();

    bf16x8 af[2], bfr[4];
#pragma unroll
    for (int mi = 0; mi < 2; ++mi) {
      int rr = wr + mi * 16 + r15;
      int s = lh ^ ((rr >> 1) & 3);
      af[mi] = *(const bf16x8*)(bb + rr * 32 + s * 8);
    }
#pragma unroll
    for (int ni = 0; ni < 4; ++ni) {
      int rr = wc + ni * 16 + r15;
      int s = lh ^ ((rr >> 1) & 3);
      bfr[ni] = *(const bf16x8*)(bb + 2048 + rr * 32 + s * 8);
    }
    __builtin_amdgcn_s_setprio(1);
#pragma unroll
    for (int mi = 0; mi < 2; ++mi)
#pragma unroll
      for (int ni = 0; ni < 4; ++ni)
        acc[mi][ni] = __builtin_amdgcn_mfma_f32_16x16x32_bf16(af[mi], bfr[ni], acc[mi][ni], 0, 0, 0);
    __builtin_amdgcn_s_setprio(0);
    __builtin_amdgcn_s_barrier();
  }
}

__global__ __launch_bounds__(256) void out_gemm(
    const bf16_t* __restrict__ A, const bf16_t* __restrict__ W,
    const float* __restrict__ bias, float* __restrict__ O)
{
  __shared__ bf16_t bufs[3 * 6144];
  f32x4 acc[2][4];
  f32x4 zero = {0.f, 0.f, 0.f, 0.f};
#pragma unroll
  for (int i = 0; i < 2; ++i)
#pragma unroll
    for (int j = 0; j < 4; ++j) acc[i][j] = zero;

  const int brow = blockIdx.x * 64, bcol = blockIdx.y * 128;
  gemm_tile_64(A, W, bufs, brow, bcol, acc);

  const int tid = threadIdx.x, l = tid & 63, w = tid >> 6;
  const int wr = (w >> 1) * 32, wc = (w & 1) * 64, lh = l >> 4, r15 = l & 15;
#pragma unroll
  for (int ni = 0; ni < 4; ++ni) {
    int col = bcol + wc + ni * 16 + r15;
    float bz = bias[col];
#pragma unroll
    for (int mi = 0; mi < 2; ++mi) {
      int row0 = brow + wr + mi * 16 + lh * 4;
#pragma unroll
      for (int j = 0; j < 4; ++j)
        O[(size_t)(row0 + j) * D_MODEL + col] = acc[mi][ni][j] + bz;
    }
  }
}

// ---------------- causal flash attention: unfolded, KVBLK=128, 40KB LDS ------
__device__ __forceinline__ void stage_k128(const bf16_t* Kg, bf16_t* Kd, int kv0, int w, int l) {
#pragma unroll
  for (int i = 0; i < 4; ++i) {
    int c = w * 4 + i;
    int row = c * 8 + (l >> 3);
    int gcol = ((l & 7) ^ ((l >> 3) & 7)) * 8;
    gload_lds16(Kg + (size_t)(kv0 + row) * D_MODEL + gcol, Kd + c * 512);
  }
}
__device__ __forceinline__ void stage_v128(const bf16_t* Vg, bf16_t* Vd, int kv0, int w, int l) {
#pragma unroll
  for (int i = 0; i < 4; ++i) {
    int c = w * 4 + i;
    int drow = c * 4 + (l >> 4);
    int gkv = ((l & 15) ^ (drow & 15)) * 8;
    gload_lds16(Vg + (size_t)drow * T_SEQ + kv0 + gkv, Vd + c * 512);
  }
}

__global__ __launch_bounds__(256) void flash_attn(
    const bf16_t* __restrict__ Qm, const bf16_t* __restrict__ Km,
    const bf16_t* __restrict__ Vtg, bf16_t* __restrict__ Om)
{
  __shared__ bf16_t Kls[128 * 64];
  __shared__ bf16_t Vls[64 * 128];
  __shared__ bf16_t Pls[4][16 * 64];

  const int tid = threadIdx.x, l = tid & 63, w = tid >> 6;
  const int lh = l >> 4, r15 = l & 15;

  const int lid = blockIdx.x;
  const int qt = 31 - (lid >> 5);
  const int bh = lid & 31;
  const int b = bh >> 4, h = bh & 15;
  const int nT = (qt >> 1) + 1;

  const size_t baseQ = (size_t)b * T_SEQ * D_MODEL + h * 64;
  const size_t baseVt = (size_t)b * (D_MODEL * T_SEQ) + (size_t)(h * 64) * T_SEQ;
  const bf16_t* Kg = Km + baseQ;
  const bf16_t* Vg = Vtg + baseVt;

  const int qw = qt * 64 + w * 16;
  const int qrow = qw + r15;
  const int sw7 = r15 & 7;

  bf16x8 qf[2];
  {
    const bf16_t* qp = Qm + baseQ + (size_t)qrow * D_MODEL + lh * 8;
    qf[0] = *(const bf16x8*)(qp);
    qf[1] = *(const bf16x8*)(qp + 32);
  }

  float l_r = 0.f;
  f32x4 o_acc[4];
  const f32x4 zero = {0.f, 0.f, 0.f, 0.f};
#pragma unroll
  for (int n = 0; n < 4; ++n) o_acc[n] = zero;

  bf16_t* P = &Pls[w][0];

  stage_k128(Kg, Kls, 0, w, l);
  stage_v128(Vg, Vls, 0, w, l);
  WAITVM(0);
  __builtin_amdgcn_s_barrier();

  for (int t = 0; t < nT; ++t) {
    const int kv0 = t * 128;
    const bool more = (t + 1 < nT);
    const bool diag = (t == nT - 1);
    const bool skip2 = diag && ((qt & 1) == 0);

    f32x4 sf[8];
    auto qk_n = [&](int n) {
      const int kvc = n * 16 + r15;
      const int sw = kvc & 7;
      bf16x8 kf0 = *(const bf16x8*)(Kls + kvc * 64 + ((lh ^ sw) * 8));
      bf16x8 kf1 = *(const bf16x8*)(Kls + kvc * 64 + (((4 + lh) ^ sw) * 8));
      f32x4 a = zero;
      a = __builtin_amdgcn_mfma_f32_16x16x32_bf16(kf0, qf[0], a, 0, 0, 0);
      a = __builtin_amdgcn_mfma_f32_16x16x32_bf16(kf1, qf[1], a, 0, 0, 0);
      sf[n] = a;
    };
    __builtin_amdgcn_s_setprio(1);
#pragma unroll
    for (int n = 0; n < 4; ++n) qk_n(n);
    __builtin_amdgcn_s_setprio(0);
    if (!skip2) {
      __builtin_amdgcn_s_setprio(1);
#pragma unroll
      for (int n = 4; n < 8; ++n) qk_n(n);
      __builtin_amdgcn_s_setprio(0);
    }

    WAITVM(0);
    __builtin_amdgcn_s_barrier();
    if (more) stage_k128(Kg, Kls, kv0 + 128, w, l);

    auto sm_half = [&](int hh, bool dm) {
#pragma unroll
      for (int n2 = 0; n2 < 4; ++n2) {
        const int n = hh * 4 + n2;
        float pv[4];
#pragma unroll
        for (int j = 0; j < 4; ++j) {
          float pp = fast_exp2(sf[n][j]);
          if (dm) {
            const int kvcol = kv0 + hh * 64 + n2 * 16 + lh * 4 + j;
            if (kvcol > qrow) pp = 0.f;
          }
          pv[j] = pp;
          l_r += pp;
        }
        bf16x4 pk = { (bf16_t)pv[0], (bf16_t)pv[1], (bf16_t)pv[2], (bf16_t)pv[3] };
        const int slot = n2 * 2 + (lh >> 1);
        *(bf16x4*)(P + r15 * 64 + ((slot ^ sw7) * 8) + (lh & 1) * 4) = pk;
      }
    };
    auto pv_half = [&](int hh) {
      bf16x8 pa0 = *(const bf16x8*)(P + r15 * 64 + ((lh ^ sw7) * 8));
      bf16x8 pa1 = *(const bf16x8*)(P + r15 * 64 + (((4 + lh) ^ sw7) * 8));
      __builtin_amdgcn_s_setprio(1);
#pragma unroll
      for (int nD = 0; nD < 4; ++nD) {
        const int d = nD * 16 + r15;
        const int b0 = (hh * 8 + lh) ^ r15;
        const int b1 = (hh * 8 + 4 + lh) ^ r15;
        bf16x8 vf0 = *(const bf16x8*)(Vls + d * 128 + b0 * 8);
        bf16x8 vf1 = *(const bf16x8*)(Vls + d * 128 + b1 * 8);
        o_acc[nD] = __builtin_amdgcn_mfma_f32_16x16x32_bf16(vf0, pa0, o_acc[nD], 0, 0, 0);
        o_acc[nD] = __builtin_amdgcn_mfma_f32_16x16x32_bf16(vf1, pa1, o_acc[nD], 0, 0, 0);
      }
      __builtin_amdgcn_s_setprio(0);
    };

    sm_half(0, diag);
    pv_half(0);
    if (!skip2) {
      sm_half(1, diag);
      pv_half(1);
    }

    WAITVM(0);
    __builtin_amdgcn_s_barrier();
    if (more) stage_v128(Vg, Vls, kv0 + 128, w, l);
  }

  float ls = l_r;
  ls += __shfl_xor(ls, 16, 64);
  ls += __shfl_xor(ls, 32, 64);
  const float invl = 1.f / ls;
  bf16_t* orow = Om + (size_t)(b * T_SEQ + qrow) * D_MODEL + h * 64;
#pragma unroll
  for (int n = 0; n < 4; ++n) {
    bf16x4 pk = { (bf16_t)(o_acc[n][0] * invl), (bf16_t)(o_acc[n][1] * invl),
                  (bf16_t)(o_acc[n][2] * invl), (bf16_t)(o_acc[n][3] * invl) };
    *(bf16x4*)(orow + n * 16 + lh * 4) = pk;
  }
}

// ---------------- host launch ----------------
extern "C" void kernel_launch(void* const* d_in, const int* in_sizes, int n_in,
                              void* d_out, int out_size, void* d_ws, size_t ws_size,
                              hipStream_t stream) {
  const float* x  = (const float*)d_in[0];
  const float* wq = (const float*)d_in[1];
  const float* bq = (const float*)d_in[2];
  const float* wk = (const float*)d_in[3];
  const float* bk = (const float*)d_in[4];
  const float* wv = (const float*)d_in[5];
  const float* bv = (const float*)d_in[6];
  const float* wo = (const float*)d_in[7];
  const float* bo = (const float*)d_in[8];

  char* ws = (char*)d_ws;
  const size_t MB = 1024 * 1024;
  bf16_t* xb  = (bf16_t*)(ws);
  bf16_t* wqb = (bf16_t*)(ws + 8 * MB);
  bf16_t* wkb = (bf16_t*)(ws + 10 * MB);
  bf16_t* wvb = (bf16_t*)(ws + 12 * MB);
  bf16_t* wob = (bf16_t*)(ws + 14 * MB);
  bf16_t* qb  = (bf16_t*)(ws + 16 * MB);
  bf16_t* kb  = (bf16_t*)(ws + 24 * MB);
  bf16_t* vtb = (bf16_t*)(ws + 32 * MB);  // V^T [B][1024][2048]
  bf16_t* ob  = (bf16_t*)(ws + 40 * MB);

  CastArgs ca;
  ca.src[0] = x;  ca.dst[0] = xb;
  ca.src[1] = wq; ca.dst[1] = wqb;
  ca.src[2] = wk; ca.dst[2] = wkb;
  ca.src[3] = wv; ca.dst[3] = wvb;
  ca.src[4] = wo; ca.dst[4] = wob;
  cast_all<<<8192, 256, 0, stream>>>(ca);

  QKVArgs qa;
  qa.A = xb;
  qa.W[0] = wqb; qa.W[1] = wkb; qa.W[2] = wvb;
  qa.bias[0] = bq; qa.bias[1] = bk; qa.bias[2] = bv;
  qa.out[0] = qb; qa.out[1] = kb; qa.out[2] = vtb;
  qkv_gemm<<<512, 256, 0, stream>>>(qa);

  flash_attn<<<1024, 256, 0, stream>>>(qb, kb, vtb, ob);

  out_gemm<<<dim3(64, 8), 256, 0, stream>>>(ob, wob, bo, (float*)d_out);
}

// Round 15
// 88.827 us; speedup vs baseline: 1.1507x; 1.0258x over previous
//
#include <hip/hip_runtime.h>
#include <hip/hip_bf16.h>

typedef __bf16 bf16_t;
typedef __bf16 bf16x8 __attribute__((ext_vector_type(8)));
typedef __bf16 bf16x4 __attribute__((ext_vector_type(4)));
typedef float f32x4 __attribute__((ext_vector_type(4)));
typedef unsigned int u32;

#define D_MODEL 1024
#define T_SEQ   2048
#define N_HEADS 16

#define WAITVM(N) asm volatile("s_waitcnt vmcnt(" #N ")" ::: "memory")

__device__ __forceinline__ void gload_lds16(const void* g, void* l) {
  __builtin_amdgcn_global_load_lds((const __attribute__((address_space(1))) u32*)g,
                                   (__attribute__((address_space(3))) u32*)l, 16, 0, 0);
}

__device__ __forceinline__ float fast_exp2(float x) {
#if __has_builtin(__builtin_amdgcn_exp2f)
  return __builtin_amdgcn_exp2f(x);
#else
  return __expf(x * 0.69314718056f);
#endif
}

// ---------------- fused fp32->bf16 cast (x + 4 weights), 8 elems/thread ------
struct CastArgs { const float* src[5]; bf16_t* dst[5]; };

__global__ __launch_bounds__(256) void cast_all(CastArgs p) {
  unsigned i = (blockIdx.x * 256u + threadIdx.x) * 8u;
  int seg; unsigned off;
  if (i < 4194304u) { seg = 0; off = i; }
  else { unsigned r = i - 4194304u; seg = 1 + (int)(r >> 20); off = r & 1048575u; }
  const float4 v0 = *(const float4*)(p.src[seg] + off);
  const float4 v1 = *(const float4*)(p.src[seg] + off + 4);
  bf16x8 o = { (bf16_t)v0.x, (bf16_t)v0.y, (bf16_t)v0.z, (bf16_t)v0.w,
               (bf16_t)v1.x, (bf16_t)v1.y, (bf16_t)v1.z, (bf16_t)v1.w };
  *(bf16x8*)(p.dst[seg] + off) = o;
}

#define QSCL 0.18033688011112042f   // 0.125 * log2(e)

// ============== fused QKV: 128x192 tile, BK=64, 256 thr, 2 blocks/CU =========
struct QKVArgs {
  const bf16_t* A;
  const bf16_t* W[3];
  const float* bias[3];
  bf16_t* out[3];
};

__global__ __launch_bounds__(256, 2) void qkv_gemm(QKVArgs p) {
  __shared__ bf16_t lds[2 * 20480];   // [buf][A:8192 | B:12288] elems

  const int tid = threadIdx.x;
  const int l = tid & 63, w = tid >> 6;
  const int lh = l >> 4, r15 = l & 15;

  const int lid = blockIdx.x;
  const int by = lid & 15, bx = lid >> 4;
  const int brow = bx * 128;
  const int gcol0 = by * 192;

  const int wr = (w >> 1) * 64;
  const int wc = (w & 1) * 96;
  const int wrc = wr >> 4;
  const int wcc = wc >> 4;
  const int sA = (lh ^ ((r15 >> 1) & 3)) * 8;
  const int roff = r15 * 32;

  const int srow = l >> 2;
  const int gs = ((l & 3) ^ ((l >> 3) & 3)) * 8;

  f32x4 acc[4][6];
  const f32x4 zero = {0.f, 0.f, 0.f, 0.f};
#pragma unroll
  for (int i = 0; i < 4; ++i)
#pragma unroll
    for (int j = 0; j < 6; ++j) acc[i][j] = zero;

  const bf16_t* A = p.A;

  auto stage = [&](bf16_t* buf, int k0) {
#pragma unroll
    for (int i = 0; i < 4; ++i) {
      int c = w * 4 + i;
      int kh = c >> 3, cc = c & 7;
      gload_lds16(A + (size_t)(brow + cc * 16 + srow) * D_MODEL + k0 + kh * 32 + gs,
                  buf + c * 512);
    }
#pragma unroll
    for (int i = 0; i < 6; ++i) {
      int g = w * 6 + i;
      int kh = g >= 12;
      int cb = g - kh * 12;
      int gcol = gcol0 + cb * 16 + srow;
      int z = gcol >> 10;
      const bf16_t* wt = (z == 0) ? p.W[0] : ((z == 1) ? p.W[1] : p.W[2]);
      gload_lds16(wt + (size_t)(gcol & 1023) * D_MODEL + k0 + kh * 32 + gs,
                  buf + 8192 + g * 512);
    }
  };

  stage(lds, 0);

  for (int t = 0; t < 16; ++t) {
    bf16_t* cur = lds + (t & 1) * 20480;
    WAITVM(0);
    __builtin_amdgcn_s_barrier();
    if (t < 15) stage(lds + ((t + 1) & 1) * 20480, (t + 1) * 64);

#pragma unroll
    for (int kh = 0; kh < 2; ++kh) {
      bf16x8 bfr[6];
#pragma unroll
      for (int ni = 0; ni < 6; ++ni)
        bfr[ni] = *(const bf16x8*)(cur + 8192 + (kh * 12 + wcc + ni) * 512 + roff + sA);
      __builtin_amdgcn_s_setprio(1);
#pragma unroll
      for (int mi = 0; mi < 4; ++mi) {
        bf16x8 af = *(const bf16x8*)(cur + (kh * 8 + wrc + mi) * 512 + roff + sA);
#pragma unroll
        for (int ni = 0; ni < 6; ++ni)
          acc[mi][ni] = __builtin_amdgcn_mfma_f32_16x16x32_bf16(af, bfr[ni], acc[mi][ni], 0, 0, 0);
      }
      __builtin_amdgcn_s_setprio(0);
    }
  }

#pragma unroll
  for (int ni = 0; ni < 6; ++ni) {
    const int col = gcol0 + wc + ni * 16 + r15;
    const int z = col >> 10;
    const int zc = col & 1023;
    const float* bias = (z == 0) ? p.bias[0] : ((z == 1) ? p.bias[1] : p.bias[2]);
    bf16_t* O = (z == 0) ? p.out[0] : ((z == 1) ? p.out[1] : p.out[2]);
    const float bz = bias[zc];
    if (z == 2) {
#pragma unroll
      for (int mi = 0; mi < 4; ++mi) {
        int row0 = brow + wr + mi * 16 + lh * 4;
        int bb = row0 >> 11, t0 = row0 & 2047;
        bf16x4 pk;
#pragma unroll
        for (int j = 0; j < 4; ++j) pk[j] = (bf16_t)(acc[mi][ni][j] + bz);
        *(bf16x4*)(O + (size_t)bb * (D_MODEL * T_SEQ) + (size_t)zc * T_SEQ + t0) = pk;
      }
    } else if (z == 0) {
#pragma unroll
      for (int mi = 0; mi < 4; ++mi) {
        int row0 = brow + wr + mi * 16 + lh * 4;
#pragma unroll
        for (int j = 0; j < 4; ++j)
          O[(size_t)(row0 + j) * D_MODEL + zc] = (bf16_t)((acc[mi][ni][j] + bz) * QSCL);
      }
    } else {
#pragma unroll
      for (int mi = 0; mi < 4; ++mi) {
        int row0 = brow + wr + mi * 16 + lh * 4;
#pragma unroll
        for (int j = 0; j < 4; ++j)
          O[(size_t)(row0 + j) * D_MODEL + zc] = (bf16_t)(acc[mi][ni][j] + bz);
      }
    }
  }
}

// ---------------- out projection: 64x128 tile, R14 handshake ----------------
// LDS = 2 x (A:4096 + B:8192) elems x 2B = 48KB -> 3 blocks/CU; grid 512 = 2/CU.
__global__ __launch_bounds__(256, 2) void out_gemm(
    const bf16_t* __restrict__ A, const bf16_t* __restrict__ W,
    const float* __restrict__ bias, float* __restrict__ O)
{
  __shared__ bf16_t lds[2 * 12288];

  const int tid = threadIdx.x;
  const int l = tid & 63, w = tid >> 6;
  const int lh = l >> 4, r15 = l & 15;

  const int brow = blockIdx.x * 64, bcol = blockIdx.y * 128;
  const int wr = (w >> 1) * 32;
  const int wc = (w & 1) * 64;
  const int wrc = wr >> 4;            // 0 or 2
  const int wcc = wc >> 4;            // 0 or 4
  const int sA = (lh ^ ((r15 >> 1) & 3)) * 8;
  const int roff = r15 * 32;

  const int srow = l >> 2;
  const int gs = ((l & 3) ^ ((l >> 3) & 3)) * 8;

  f32x4 acc[2][4];
  const f32x4 zero = {0.f, 0.f, 0.f, 0.f};
#pragma unroll
  for (int i = 0; i < 2; ++i)
#pragma unroll
    for (int j = 0; j < 4; ++j) acc[i][j] = zero;

  auto stage = [&](bf16_t* buf, int k0) {
#pragma unroll
    for (int i = 0; i < 2; ++i) {           // A: 8 units (kh*4 + cc)
      int c = w * 2 + i;
      int kh = c >> 2, cc = c & 3;
      gload_lds16(A + (size_t)(brow + cc * 16 + srow) * D_MODEL + k0 + kh * 32 + gs,
                  buf + c * 512);
    }
#pragma unroll
    for (int i = 0; i < 4; ++i) {           // B: 16 units (kh*8 + cb)
      int g = w * 4 + i;
      int kh = g >> 3, cb = g & 7;
      gload_lds16(W + (size_t)(bcol + cb * 16 + srow) * D_MODEL + k0 + kh * 32 + gs,
                  buf + 4096 + g * 512);
    }
  };

  stage(lds, 0);

  for (int t = 0; t < 16; ++t) {
    bf16_t* cur = lds + (t & 1) * 12288;
    WAITVM(0);
    __builtin_amdgcn_s_barrier();
    if (t < 15) stage(lds + ((t + 1) & 1) * 12288, (t + 1) * 64);

#pragma unroll
    for (int kh = 0; kh < 2; ++kh) {
      bf16x8 bfr[4];
#pragma unroll
      for (int ni = 0; ni < 4; ++ni)
        bfr[ni] = *(const bf16x8*)(cur + 4096 + (kh * 8 + wcc + ni) * 512 + roff + sA);
      __builtin_amdgcn_s_setprio(1);
#pragma unroll
      for (int mi = 0; mi < 2; ++mi) {
        bf16x8 af = *(const bf16x8*)(cur + (kh * 4 + wrc + mi) * 512 + roff + sA);
#pragma unroll
        for (int ni = 0; ni < 4; ++ni)
          acc[mi][ni] = __builtin_amdgcn_mfma_f32_16x16x32_bf16(af, bfr[ni], acc[mi][ni], 0, 0, 0);
      }
      __builtin_amdgcn_s_setprio(0);
    }
  }

#pragma unroll
  for (int ni = 0; ni < 4; ++ni) {
    int col = bcol + wc + ni * 16 + r15;
    float bz = bias[col];
#pragma unroll
    for (int mi = 0; mi < 2; ++mi) {
      int row0 = brow + wr + mi * 16 + lh * 4;
#pragma unroll
      for (int j = 0; j < 4; ++j)
        O[(size_t)(row0 + j) * D_MODEL + col] = acc[mi][ni][j] + bz;
    }
  }
}

// ---------------- causal flash attention: balanced, KVBLK=128, 40KB LDS ------
// 1024 blocks: g = lid>>5 -> (r = g>>3, s = g&7) -> qt table {31-s,16+s,15-s,s}
// gives every CU slot exactly 34 tile-units (LPT: big qt dispatch first).
// bh = lid&31 (head pinned to one XCD). Body identical to R13/R14.
__device__ __forceinline__ void stage_k128(const bf16_t* Kg, bf16_t* Kd, int kv0, int w, int l) {
#pragma unroll
  for (int i = 0; i < 4; ++i) {
    int c = w * 4 + i;
    int row = c * 8 + (l >> 3);
    int gcol = ((l & 7) ^ ((l >> 3) & 7)) * 8;
    gload_lds16(Kg + (size_t)(kv0 + row) * D_MODEL + gcol, Kd + c * 512);
  }
}
__device__ __forceinline__ void stage_v128(const bf16_t* Vg, bf16_t* Vd, int kv0, int w, int l) {
#pragma unroll
  for (int i = 0; i < 4; ++i) {
    int c = w * 4 + i;
    int drow = c * 4 + (l >> 4);
    int gkv = ((l & 15) ^ (drow & 15)) * 8;
    gload_lds16(Vg + (size_t)drow * T_SEQ + kv0 + gkv, Vd + c * 512);
  }
}

__global__ __launch_bounds__(256) void flash_attn(
    const bf16_t* __restrict__ Qm, const bf16_t* __restrict__ Km,
    const bf16_t* __restrict__ Vtg, bf16_t* __restrict__ Om)
{
  __shared__ bf16_t Kls[128 * 64];
  __shared__ bf16_t Vls[64 * 128];
  __shared__ bf16_t Pls[4][16 * 64];

  const int tid = threadIdx.x, l = tid & 63, w = tid >> 6;
  const int lh = l >> 4, r15 = l & 15;

  const int lid = blockIdx.x;
  const int g = lid >> 5;
  const int r = g >> 3, s = g & 7;
  const int qt = (r == 0) ? (31 - s) : ((r == 1) ? (16 + s) : ((r == 2) ? (15 - s) : s));
  const int bh = lid & 31;
  const int b = bh >> 4, h = bh & 15;
  const int nT = (qt >> 1) + 1;

  const size_t baseQ = (size_t)b * T_SEQ * D_MODEL + h * 64;
  const size_t baseVt = (size_t)b * (D_MODEL * T_SEQ) + (size_t)(h * 64) * T_SEQ;
  const bf16_t* Kg = Km + baseQ;
  const bf16_t* Vg = Vtg + baseVt;

  const int qw = qt * 64 + w * 16;
  const int qrow = qw + r15;
  const int sw7 = r15 & 7;

  bf16x8 qf[2];
  {
    const bf16_t* qp = Qm + baseQ + (size_t)qrow * D_MODEL + lh * 8;
    qf[0] = *(const bf16x8*)(qp);
    qf[1] = *(const bf16x8*)(qp + 32);
  }

  float l_r = 0.f;
  f32x4 o_acc[4];
  const f32x4 zero = {0.f, 0.f, 0.f, 0.f};
#pragma unroll
  for (int n = 0; n < 4; ++n) o_acc[n] = zero;

  bf16_t* P = &Pls[w][0];

  stage_k128(Kg, Kls, 0, w, l);
  stage_v128(Vg, Vls, 0, w, l);
  WAITVM(0);
  __builtin_amdgcn_s_barrier();

  for (int t = 0; t < nT; ++t) {
    const int kv0 = t * 128;
    const bool more = (t + 1 < nT);
    const bool diag = (t == nT - 1);
    const bool skip2 = diag && ((qt & 1) == 0);

    f32x4 sf[8];
    auto qk_n = [&](int n) {
      const int kvc = n * 16 + r15;
      const int sw = kvc & 7;
      bf16x8 kf0 = *(const bf16x8*)(Kls + kvc * 64 + ((lh ^ sw) * 8));
      bf16x8 kf1 = *(const bf16x8*)(Kls + kvc * 64 + (((4 + lh) ^ sw) * 8));
      f32x4 a = zero;
      a = __builtin_amdgcn_mfma_f32_16x16x32_bf16(kf0, qf[0], a, 0, 0, 0);
      a = __builtin_amdgcn_mfma_f32_16x16x32_bf16(kf1, qf[1], a, 0, 0, 0);
      sf[n] = a;
    };
    __builtin_amdgcn_s_setprio(1);
#pragma unroll
    for (int n = 0; n < 4; ++n) qk_n(n);
    __builtin_amdgcn_s_setprio(0);
    if (!skip2) {
      __builtin_amdgcn_s_setprio(1);
#pragma unroll
      for (int n = 4; n < 8; ++n) qk_n(n);
      __builtin_amdgcn_s_setprio(0);
    }

    WAITVM(0);
    __builtin_amdgcn_s_barrier();
    if (more) stage_k128(Kg, Kls, kv0 + 128, w, l);

    auto sm_half = [&](int hh, bool dm) {
#pragma unroll
      for (int n2 = 0; n2 < 4; ++n2) {
        const int n = hh * 4 + n2;
        float pv[4];
#pragma unroll
        for (int j = 0; j < 4; ++j) {
          float pp = fast_exp2(sf[n][j]);
          if (dm) {
            const int kvcol = kv0 + hh * 64 + n2 * 16 + lh * 4 + j;
            if (kvcol > qrow) pp = 0.f;
          }
          pv[j] = pp;
          l_r += pp;
        }
        bf16x4 pk = { (bf16_t)pv[0], (bf16_t)pv[1], (bf16_t)pv[2], (bf16_t)pv[3] };
        const int slot = n2 * 2 + (lh >> 1);
        *(bf16x4*)(P + r15 * 64 + ((slot ^ sw7) * 8) + (lh & 1) * 4) = pk;
      }
    };
    auto pv_half = [&](int hh) {
      bf16x8 pa0 = *(const bf16x8*)(P + r15 * 64 + ((lh ^ sw7) * 8));
      bf16x8 pa1 = *(const bf16x8*)(P + r15 * 64 + (((4 + lh) ^ sw7) * 8));
      __builtin_amdgcn_s_setprio(1);
#pragma unroll
      for (int nD = 0; nD < 4; ++nD) {
        const int d = nD * 16 + r15;
        const int b0 = (hh * 8 + lh) ^ r15;
        const int b1 = (hh * 8 + 4 + lh) ^ r15;
        bf16x8 vf0 = *(const bf16x8*)(Vls + d * 128 + b0 * 8);
        bf16x8 vf1 = *(const bf16x8*)(Vls + d * 128 + b1 * 8);
        o_acc[nD] = __builtin_amdgcn_mfma_f32_16x16x32_bf16(vf0, pa0, o_acc[nD], 0, 0, 0);
        o_acc[nD] = __builtin_amdgcn_mfma_f32_16x16x32_bf16(vf1, pa1, o_acc[nD], 0, 0, 0);
      }
      __builtin_amdgcn_s_setprio(0);
    };

    sm_half(0, diag);
    pv_half(0);
    if (!skip2) {
      sm_half(1, diag);
      pv_half(1);
    }

    WAITVM(0);
    __builtin_amdgcn_s_barrier();
    if (more) stage_v128(Vg, Vls, kv0 + 128, w, l);
  }

  float ls = l_r;
  ls += __shfl_xor(ls, 16, 64);
  ls += __shfl_xor(ls, 32, 64);
  const float invl = 1.f / ls;
  bf16_t* orow = Om + (size_t)(b * T_SEQ + qrow) * D_MODEL + h * 64;
#pragma unroll
  for (int n = 0; n < 4; ++n) {
    bf16x4 pk = { (bf16_t)(o_acc[n][0] * invl), (bf16_t)(o_acc[n][1] * invl),
                  (bf16_t)(o_acc[n][2] * invl), (bf16_t)(o_acc[n][3] * invl) };
    *(bf16x4*)(orow + n * 16 + lh * 4) = pk;
  }
}

// ---------------- host launch ----------------
extern "C" void kernel_launch(void* const* d_in, const int* in_sizes, int n_in,
                              void* d_out, int out_size, void* d_ws, size_t ws_size,
                              hipStream_t stream) {
  const float* x  = (const float*)d_in[0];
  const float* wq = (const float*)d_in[1];
  const float* bq = (const float*)d_in[2];
  const float* wk = (const float*)d_in[3];
  const float* bk = (const float*)d_in[4];
  const float* wv = (const float*)d_in[5];
  const float* bv = (const float*)d_in[6];
  const float* wo = (const float*)d_in[7];
  const float* bo = (const float*)d_in[8];

  char* ws = (char*)d_ws;
  const size_t MB = 1024 * 1024;
  bf16_t* xb  = (bf16_t*)(ws);
  bf16_t* wqb = (bf16_t*)(ws + 8 * MB);
  bf16_t* wkb = (bf16_t*)(ws + 10 * MB);
  bf16_t* wvb = (bf16_t*)(ws + 12 * MB);
  bf16_t* wob = (bf16_t*)(ws + 14 * MB);
  bf16_t* qb  = (bf16_t*)(ws + 16 * MB);
  bf16_t* kb  = (bf16_t*)(ws + 24 * MB);
  bf16_t* vtb = (bf16_t*)(ws + 32 * MB);  // V^T [B][1024][2048]
  bf16_t* ob  = (bf16_t*)(ws + 40 * MB);

  CastArgs ca;
  ca.src[0] = x;  ca.dst[0] = xb;
  ca.src[1] = wq; ca.dst[1] = wqb;
  ca.src[2] = wk; ca.dst[2] = wkb;
  ca.src[3] = wv; ca.dst[3] = wvb;
  ca.src[4] = wo; ca.dst[4] = wob;
  cast_all<<<4096, 256, 0, stream>>>(ca);

  QKVArgs qa;
  qa.A = xb;
  qa.W[0] = wqb; qa.W[1] = wkb; qa.W[2] = wvb;
  qa.bias[0] = bq; qa.bias[1] = bk; qa.bias[2] = bv;
  qa.out[0] = qb; qa.out[1] = kb; qa.out[2] = vtb;
  qkv_gemm<<<512, 256, 0, stream>>>(qa);

  flash_attn<<<1024, 256, 0, stream>>>(qb, kb, vtb, ob);

  out_gemm<<<dim3(64, 8), 256, 0, stream>>>(ob, wob, bo, (float*)d_out);
}